// Round 1
// baseline (18866.376 us; speedup 1.0000x reference)
//
#include <hip/hip_runtime.h>
#include <hip/hip_bf16.h>
#include <math.h>

#define BATCH 2
#define LSEQ 577
#define DM 1024
#define DI 2048
#define DSTATE 16
#define DCONV 4
#define DTR 64
#define NLAYERS 24
#define NP 576
#define MROWS (BATCH*LSEQ)   // 1154

// ---------------- im2col for patch embedding ----------------
__global__ void im2col_k(const float* __restrict__ x, float* __restrict__ patches) {
  int idx = blockIdx.x * 256 + threadIdx.x;
  if (idx >= BATCH * NP * 768) return;
  int col = idx % 768, row = idx / 768;
  int b = row / NP, p = row % NP;
  int ph = p / 24, pw = p % 24;
  int c = col >> 8, r = col & 255, kh = r >> 4, kw = r & 15;
  patches[idx] = x[(((size_t)(b * 3 + c) * 384) + ph * 16 + kh) * 384 + pw * 16 + kw];
}

// ---------------- generic fp32 GEMM:  C(M,N) = A(M,K;lda) * Bw(N,K)^T ----------------
// mode 0: C = acc            (ldc = N)
// mode 1: C += acc           (ldc = N)
// mode 2: C = softplus(acc + bias[n])
// mode 3: patch-embed scatter: out[b*LSEQ+1+p][n] = acc + bias[n] + pos[(1+p)*DM+n]
#define GBM 64
#define GBN 64
#define GBK 16

__global__ __launch_bounds__(256) void gemm_nt(
    const float* __restrict__ A, int lda,
    const float* __restrict__ Bw,
    float* __restrict__ C,
    int M, int N, int K, int mode,
    const float* __restrict__ bias, const float* __restrict__ pos)
{
  __shared__ float As[GBK][GBM];
  __shared__ float Bs[GBK][GBN];
  int tid = threadIdx.x;
  int bm = blockIdx.y * GBM, bn = blockIdx.x * GBN;
  int lrow = tid >> 2, lk = (tid & 3) << 2;
  int tm = (tid >> 4) << 2, tn = (tid & 15) << 2;
  float acc[4][4] = {};
  for (int k0 = 0; k0 < K; k0 += GBK) {
    float4 va = make_float4(0.f, 0.f, 0.f, 0.f);
    float4 vb = make_float4(0.f, 0.f, 0.f, 0.f);
    if (bm + lrow < M) va = *(const float4*)(A + (size_t)(bm + lrow) * lda + k0 + lk);
    if (bn + lrow < N) vb = *(const float4*)(Bw + (size_t)(bn + lrow) * K + k0 + lk);
    As[lk + 0][lrow] = va.x; As[lk + 1][lrow] = va.y; As[lk + 2][lrow] = va.z; As[lk + 3][lrow] = va.w;
    Bs[lk + 0][lrow] = vb.x; Bs[lk + 1][lrow] = vb.y; Bs[lk + 2][lrow] = vb.z; Bs[lk + 3][lrow] = vb.w;
    __syncthreads();
    #pragma unroll
    for (int k = 0; k < GBK; ++k) {
      float4 a4 = *(const float4*)&As[k][tm];
      float4 b4 = *(const float4*)&Bs[k][tn];
      float av[4] = {a4.x, a4.y, a4.z, a4.w};
      float bv[4] = {b4.x, b4.y, b4.z, b4.w};
      #pragma unroll
      for (int i = 0; i < 4; ++i)
        #pragma unroll
        for (int j = 0; j < 4; ++j) acc[i][j] += av[i] * bv[j];
    }
    __syncthreads();
  }
  #pragma unroll
  for (int i = 0; i < 4; ++i) {
    int m = bm + tm + i;
    if (m >= M) break;
    #pragma unroll
    for (int j = 0; j < 4; ++j) {
      int n = bn + tn + j;
      if (n >= N) continue;
      float v = acc[i][j];
      if (mode == 0) {
        C[(size_t)m * N + n] = v;
      } else if (mode == 1) {
        C[(size_t)m * N + n] += v;
      } else if (mode == 2) {
        float t = v + bias[n];
        C[(size_t)m * N + n] = (t > 20.f) ? t : log1pf(__expf(t));
      } else {
        int b = m / NP, p = m % NP;
        size_t orow = (size_t)(b * LSEQ + 1 + p);
        C[orow * DM + n] = v + bias[n] + pos[(size_t)(1 + p) * DM + n];
      }
    }
  }
}

// ---------------- cls token row ----------------
__global__ void cls_k(const float* __restrict__ cls, const float* __restrict__ pos,
                      float* __restrict__ out) {
  int n = blockIdx.x * 256 + threadIdx.x;
  if (n >= DM) return;
  float v = cls[n] + pos[n];
  out[n] = v;
  out[(size_t)LSEQ * DM + n] = v;
}

// ---------------- LayerNorm (one block per row of 1024) ----------------
__global__ __launch_bounds__(256) void ln_k(const float* __restrict__ tok,
    const float* __restrict__ w, const float* __restrict__ bsh,
    float* __restrict__ h) {
  int row = blockIdx.x;
  const float* xr = tok + (size_t)row * DM;
  int tid = threadIdx.x;
  float v[4];
  #pragma unroll
  for (int i = 0; i < 4; ++i) v[i] = xr[tid + 256 * i];
  float s = v[0] + v[1] + v[2] + v[3];
  float s2 = v[0] * v[0] + v[1] * v[1] + v[2] * v[2] + v[3] * v[3];
  #pragma unroll
  for (int off = 32; off; off >>= 1) { s += __shfl_xor(s, off); s2 += __shfl_xor(s2, off); }
  __shared__ float ps[4], ps2[4];
  if ((tid & 63) == 0) { ps[tid >> 6] = s; ps2[tid >> 6] = s2; }
  __syncthreads();
  s = ps[0] + ps[1] + ps[2] + ps[3];
  s2 = ps2[0] + ps2[1] + ps2[2] + ps2[3];
  float mean = s * (1.f / DM);
  float var = s2 * (1.f / DM) - mean * mean;
  float inv = rsqrtf(var + 1e-5f);
  #pragma unroll
  for (int i = 0; i < 4; ++i) {
    int c = tid + 256 * i;
    h[(size_t)row * DM + c] = (v[i] - mean) * inv * w[c] + bsh[c];
  }
}

// ---------------- causal depthwise conv (k=4) + bias + silu ----------------
__global__ void conv_silu_k(const float* __restrict__ xz, const float* __restrict__ cw,
                            const float* __restrict__ cb, float* __restrict__ u) {
  int idx = blockIdx.x * 256 + threadIdx.x;
  if (idx >= BATCH * LSEQ * DI) return;
  int d = idx & (DI - 1);
  int bl = idx >> 11;
  int l = bl % LSEQ, b = bl / LSEQ;
  float acc = cb[d];
  const float* base = xz + (size_t)b * LSEQ * 4096 + d;
  #pragma unroll
  for (int k = 0; k < 4; ++k) {
    int ll = l - 3 + k;
    if (ll >= 0) acc += base[(size_t)ll * 4096] * cw[d * 4 + k];
  }
  u[idx] = acc / (1.f + __expf(-acc));
}

// ---------------- selective scan: one thread per (b,d), 16 states in regs ----------------
__global__ __launch_bounds__(256) void scan_k(
    const float* __restrict__ dt, const float* __restrict__ u,
    const float* __restrict__ dbl, const float* __restrict__ xz,
    const float* __restrict__ alog, const float* __restrict__ dsk,
    float* __restrict__ y)
{
  int b = blockIdx.y;
  int d = blockIdx.x * 256 + threadIdx.x;
  float Ad[DSTATE];
  #pragma unroll
  for (int s = 0; s < DSTATE; ++s) Ad[s] = -__expf(alog[d * DSTATE + s]);
  float Dv = dsk[d];
  float h[DSTATE] = {};
  const float* dblb = dbl + (size_t)b * LSEQ * 96;
  size_t rowoff = (size_t)b * LSEQ;
  for (int t = 0; t < LSEQ; ++t) {
    size_t ro = rowoff + t;
    float dtv = dt[ro * DI + d];
    float uv = u[ro * DI + d];
    float du = dtv * uv;
    const float* r = dblb + (size_t)t * 96;
    float yv = 0.f;
    #pragma unroll
    for (int s = 0; s < DSTATE; ++s) {
      h[s] = __expf(dtv * Ad[s]) * h[s] + du * r[64 + s];
      yv += h[s] * r[80 + s];
    }
    float z = xz[ro * 4096 + DI + d];
    y[ro * DI + d] = (yv + Dv * uv) * (z / (1.f + __expf(-z)));
  }
}

extern "C" void kernel_launch(void* const* d_in, const int* in_sizes, int n_in,
                              void* d_out, int out_size, void* d_ws, size_t ws_size,
                              hipStream_t stream) {
  const float* x         = (const float*)d_in[0];
  const float* patch_w   = (const float*)d_in[1];
  const float* patch_b   = (const float*)d_in[2];
  const float* cls_token = (const float*)d_in[3];
  const float* pos_embed = (const float*)d_in[4];
  const float* ln_w      = (const float*)d_in[5];
  const float* ln_b      = (const float*)d_in[6];
  const float* in_proj_w = (const float*)d_in[7];
  const float* conv_w    = (const float*)d_in[8];
  const float* conv_b    = (const float*)d_in[9];
  const float* x_proj_w  = (const float*)d_in[10];
  const float* dt_proj_w = (const float*)d_in[11];
  const float* dt_proj_b = (const float*)d_in[12];
  const float* A_log     = (const float*)d_in[13];
  const float* D_skip    = (const float*)d_in[14];
  const float* out_proj_w= (const float*)d_in[15];
  float* tok = (float*)d_out;
  float* ws  = (float*)d_ws;

  float* h_buf   = ws;                       // 1,181,696
  float* xz_buf  = h_buf + 1181696;          // 4,726,784 (aliased by patches)
  float* patches = xz_buf;                   // 884,736 (used only before layers)
  float* u_buf   = xz_buf + 4726784;         // 2,363,392
  float* dbl_buf = u_buf + 2363392;          // 110,784
  float* dt_buf  = dbl_buf + 110784;         // 2,363,392
  float* y_buf   = dt_buf + 2363392;         // 2,363,392
  // total ~52.4 MB of d_ws

  // ---- patch embed + pos ----
  im2col_k<<<(BATCH * NP * 768 + 255) / 256, 256, 0, stream>>>(x, patches);
  {
    dim3 gp(DM / GBN, (BATCH * NP + GBM - 1) / GBM);
    gemm_nt<<<gp, 256, 0, stream>>>(patches, 768, patch_w, tok,
                                    BATCH * NP, DM, 768, 3, patch_b, pos_embed);
  }
  cls_k<<<(DM + 255) / 256, 256, 0, stream>>>(cls_token, pos_embed, tok);

  // ---- 24 mamba layers ----
  for (int l = 0; l < NLAYERS; ++l) {
    ln_k<<<MROWS, 256, 0, stream>>>(tok, ln_w + l * DM, ln_b + l * DM, h_buf);

    dim3 g1((2 * DI) / GBN, (MROWS + GBM - 1) / GBM);
    gemm_nt<<<g1, 256, 0, stream>>>(h_buf, DM, in_proj_w + (size_t)l * 2 * DI * DM,
                                    xz_buf, MROWS, 2 * DI, DM, 0, nullptr, nullptr);

    conv_silu_k<<<(BATCH * LSEQ * DI + 255) / 256, 256, 0, stream>>>(
        xz_buf, conv_w + (size_t)l * DI * DCONV, conv_b + (size_t)l * DI, u_buf);

    dim3 g2((96 + GBN - 1) / GBN, (MROWS + GBM - 1) / GBM);
    gemm_nt<<<g2, 256, 0, stream>>>(u_buf, DI, x_proj_w + (size_t)l * 96 * DI,
                                    dbl_buf, MROWS, 96, DI, 0, nullptr, nullptr);

    dim3 g3(DI / GBN, (MROWS + GBM - 1) / GBM);
    gemm_nt<<<g3, 256, 0, stream>>>(dbl_buf, 96, dt_proj_w + (size_t)l * DI * DTR,
                                    dt_buf, MROWS, DI, DTR, 2, dt_proj_b + (size_t)l * DI, nullptr);

    dim3 gs(DI / 256, BATCH);
    scan_k<<<gs, 256, 0, stream>>>(dt_buf, u_buf, dbl_buf, xz_buf,
                                   A_log + (size_t)l * DI * DSTATE, D_skip + (size_t)l * DI, y_buf);

    dim3 g4(DM / GBN, (MROWS + GBM - 1) / GBM);
    gemm_nt<<<g4, 256, 0, stream>>>(y_buf, DI, out_proj_w + (size_t)l * DM * DI,
                                    tok, MROWS, DM, DI, 1, nullptr, nullptr);
  }
}

// Round 2
// 6852.290 us; speedup vs baseline: 2.7533x; 2.7533x over previous
//
#include <hip/hip_runtime.h>
#include <hip/hip_bf16.h>
#include <math.h>

#define BATCH 2
#define LSEQ 577
#define DM 1024
#define DI 2048
#define DSTATE 16
#define DCONV 4
#define DTR 64
#define NLAYERS 24
#define NP 576
#define MROWS (BATCH*LSEQ)   // 1154
#define NC 16
#define LC 37                // ceil(577/16)

typedef __attribute__((ext_vector_type(8))) short short8v;
typedef __attribute__((ext_vector_type(4))) float f32x4;

__device__ __forceinline__ ushort f2bf(float f) {
  unsigned int b = __float_as_uint(f);
  unsigned int r = (b + 0x7FFFu + ((b >> 16) & 1u)) >> 16;
  return (ushort)r;
}

__device__ __forceinline__ void gload16(const void* g, void* l) {
  __builtin_amdgcn_global_load_lds(
      (const __attribute__((address_space(1))) unsigned int*)g,
      (__attribute__((address_space(3))) unsigned int*)l, 16, 0, 0);
}

// ---------------- fp32 -> bf16 conversion (RNE), 4 elems/thread ----------------
__global__ void f2bf_k(const float* __restrict__ in, ushort* __restrict__ out, int n) {
  int i = (blockIdx.x * 256 + threadIdx.x) * 4;
  if (i >= n) return;
  float4 v = *(const float4*)(in + i);
  ushort4 o;
  o.x = f2bf(v.x); o.y = f2bf(v.y); o.z = f2bf(v.z); o.w = f2bf(v.w);
  *(ushort4*)(out + i) = o;
}

// ---------------- bf16 MFMA GEMM: C(M,N) fp32 = A(M,K) * W(N,K)^T ----------------
// BM=BN=64, BK=64. 4 waves; wave w owns rows [w*16,w*16+16) x 64 cols.
// LDS: A 64x64bf16 (8KB, 128B rows) at 0; B same at 8192. XOR-swizzle (row&7)<<4
// applied on read AND on pre-swizzled global source (global_load_lds writes linear).
__global__ __launch_bounds__(256) void gemm_bf16(
    const ushort* __restrict__ A, const ushort* __restrict__ W,
    float* __restrict__ C, int M, int N, int K, int accum)
{
  __shared__ char lds[16384];
  int tid = threadIdx.x;
  int lane = tid & 63, w = tid >> 6;
  int bm = blockIdx.y * 64, bn = blockIdx.x * 64;

  // staging: thread t covers LDS offset c*4096 + t*16  (row = c*32 + (t>>3))
  int srow = tid >> 3;
  int col = ((tid & 7) ^ (srow & 7)) << 3;   // pre-swizzled source column (elems)
  int ra0 = bm + srow;      if (ra0 > M - 1) ra0 = M - 1;
  int ra1 = bm + 32 + srow; if (ra1 > M - 1) ra1 = M - 1;
  const ushort* ga0 = A + (size_t)ra0 * K + col;
  const ushort* ga1 = A + (size_t)ra1 * K + col;
  const ushort* gb0 = W + (size_t)(bn + srow) * K + col;
  const ushort* gb1 = W + (size_t)(bn + 32 + srow) * K + col;
  char* la0 = lds + (w << 10);
  char* la1 = lds + 4096 + (w << 10);
  char* lb0 = lds + 8192 + (w << 10);
  char* lb1 = lds + 12288 + (w << 10);

  int fr = lane & 15;
  int fsw = (fr & 7) << 4;
  int fk = (lane >> 4) << 4;        // byte offset of lane's 16B within 64B half-row
  int aoff = (w * 16 + fr) * 128;

  f32x4 acc0 = {0.f, 0.f, 0.f, 0.f};
  f32x4 acc1 = {0.f, 0.f, 0.f, 0.f};
  f32x4 acc2 = {0.f, 0.f, 0.f, 0.f};
  f32x4 acc3 = {0.f, 0.f, 0.f, 0.f};

  for (int k0 = 0; k0 < K; k0 += 64) {
    gload16(ga0 + k0, la0);
    gload16(ga1 + k0, la1);
    gload16(gb0 + k0, lb0);
    gload16(gb1 + k0, lb1);
    __syncthreads();
    #pragma unroll
    for (int ks = 0; ks < 2; ++ks) {
      int cb = ks * 64 + fk;
      short8v af = *(const short8v*)(lds + aoff + (cb ^ fsw));
      short8v bf0 = *(const short8v*)(lds + 8192 + (0 * 16 + fr) * 128 + (cb ^ fsw));
      short8v bf1 = *(const short8v*)(lds + 8192 + (1 * 16 + fr) * 128 + (cb ^ fsw));
      short8v bf2 = *(const short8v*)(lds + 8192 + (2 * 16 + fr) * 128 + (cb ^ fsw));
      short8v bf3 = *(const short8v*)(lds + 8192 + (3 * 16 + fr) * 128 + (cb ^ fsw));
      acc0 = __builtin_amdgcn_mfma_f32_16x16x32_bf16(af, bf0, acc0, 0, 0, 0);
      acc1 = __builtin_amdgcn_mfma_f32_16x16x32_bf16(af, bf1, acc1, 0, 0, 0);
      acc2 = __builtin_amdgcn_mfma_f32_16x16x32_bf16(af, bf2, acc2, 0, 0, 0);
      acc3 = __builtin_amdgcn_mfma_f32_16x16x32_bf16(af, bf3, acc3, 0, 0, 0);
    }
    __syncthreads();
  }

  int cm = bm + w * 16 + ((lane >> 4) << 2);
  int cn = bn + fr;
  #pragma unroll
  for (int j = 0; j < 4; ++j) {
    int m = cm + j;
    if (m >= M) break;
    float* cr = C + (size_t)m * N + cn;
    if (accum) {
      cr[0]  += acc0[j]; cr[16] += acc1[j]; cr[32] += acc2[j]; cr[48] += acc3[j];
    } else {
      cr[0]  = acc0[j]; cr[16] = acc1[j]; cr[32] = acc2[j]; cr[48] = acc3[j];
    }
  }
}

// ---------------- im2col for patch embedding ----------------
__global__ void im2col_k(const float* __restrict__ x, float* __restrict__ patches) {
  int idx = blockIdx.x * 256 + threadIdx.x;
  if (idx >= BATCH * NP * 768) return;
  int col = idx % 768, row = idx / 768;
  int b = row / NP, p = row % NP;
  int ph = p / 24, pw = p % 24;
  int c = col >> 8, r = col & 255, kh = r >> 4, kw = r & 15;
  patches[idx] = x[(((size_t)(b * 3 + c) * 384) + ph * 16 + kh) * 384 + pw * 16 + kw];
}

// ---------------- generic fp32 GEMM (small GEMMs + patch embed) ----------------
// mode 0: C = acc ; mode 2: C = softplus(acc+bias[n]) ; mode 3: patch scatter
#define GBM 64
#define GBN 64
#define GBK 16

__global__ __launch_bounds__(256) void gemm_nt(
    const float* __restrict__ A, int lda,
    const float* __restrict__ Bw,
    float* __restrict__ C,
    int M, int N, int K, int mode,
    const float* __restrict__ bias, const float* __restrict__ pos)
{
  __shared__ float As[GBK][GBM];
  __shared__ float Bs[GBK][GBN];
  int tid = threadIdx.x;
  int bm = blockIdx.y * GBM, bn = blockIdx.x * GBN;
  int lrow = tid >> 2, lk = (tid & 3) << 2;
  int tm = (tid >> 4) << 2, tn = (tid & 15) << 2;
  float acc[4][4] = {};
  for (int k0 = 0; k0 < K; k0 += GBK) {
    float4 va = make_float4(0.f, 0.f, 0.f, 0.f);
    float4 vb = make_float4(0.f, 0.f, 0.f, 0.f);
    if (bm + lrow < M) va = *(const float4*)(A + (size_t)(bm + lrow) * lda + k0 + lk);
    if (bn + lrow < N) vb = *(const float4*)(Bw + (size_t)(bn + lrow) * K + k0 + lk);
    As[lk + 0][lrow] = va.x; As[lk + 1][lrow] = va.y; As[lk + 2][lrow] = va.z; As[lk + 3][lrow] = va.w;
    Bs[lk + 0][lrow] = vb.x; Bs[lk + 1][lrow] = vb.y; Bs[lk + 2][lrow] = vb.z; Bs[lk + 3][lrow] = vb.w;
    __syncthreads();
    #pragma unroll
    for (int k = 0; k < GBK; ++k) {
      float4 a4 = *(const float4*)&As[k][tm];
      float4 b4 = *(const float4*)&Bs[k][tn];
      float av[4] = {a4.x, a4.y, a4.z, a4.w};
      float bv[4] = {b4.x, b4.y, b4.z, b4.w};
      #pragma unroll
      for (int i = 0; i < 4; ++i)
        #pragma unroll
        for (int j = 0; j < 4; ++j) acc[i][j] += av[i] * bv[j];
    }
    __syncthreads();
  }
  #pragma unroll
  for (int i = 0; i < 4; ++i) {
    int m = bm + tm + i;
    if (m >= M) break;
    #pragma unroll
    for (int j = 0; j < 4; ++j) {
      int n = bn + tn + j;
      if (n >= N) continue;
      float v = acc[i][j];
      if (mode == 0) {
        C[(size_t)m * N + n] = v;
      } else if (mode == 2) {
        float t = v + bias[n];
        C[(size_t)m * N + n] = (t > 20.f) ? t : log1pf(__expf(t));
      } else {
        int b = m / NP, p = m % NP;
        size_t orow = (size_t)(b * LSEQ + 1 + p);
        C[orow * DM + n] = v + bias[n] + pos[(size_t)(1 + p) * DM + n];
      }
    }
  }
}

// ---------------- cls token row ----------------
__global__ void cls_k(const float* __restrict__ cls, const float* __restrict__ pos,
                      float* __restrict__ out) {
  int n = blockIdx.x * 256 + threadIdx.x;
  if (n >= DM) return;
  float v = cls[n] + pos[n];
  out[n] = v;
  out[(size_t)LSEQ * DM + n] = v;
}

// ---------------- LayerNorm -> bf16 ----------------
__global__ __launch_bounds__(256) void ln_k(const float* __restrict__ tok,
    const float* __restrict__ w, const float* __restrict__ bsh,
    ushort* __restrict__ h) {
  int row = blockIdx.x;
  const float* xr = tok + (size_t)row * DM;
  int tid = threadIdx.x;
  float v[4];
  #pragma unroll
  for (int i = 0; i < 4; ++i) v[i] = xr[tid + 256 * i];
  float s = v[0] + v[1] + v[2] + v[3];
  float s2 = v[0] * v[0] + v[1] * v[1] + v[2] * v[2] + v[3] * v[3];
  #pragma unroll
  for (int off = 32; off; off >>= 1) { s += __shfl_xor(s, off); s2 += __shfl_xor(s2, off); }
  __shared__ float ps[4], ps2[4];
  if ((tid & 63) == 0) { ps[tid >> 6] = s; ps2[tid >> 6] = s2; }
  __syncthreads();
  s = ps[0] + ps[1] + ps[2] + ps[3];
  s2 = ps2[0] + ps2[1] + ps2[2] + ps2[3];
  float mean = s * (1.f / DM);
  float var = s2 * (1.f / DM) - mean * mean;
  float inv = rsqrtf(var + 1e-5f);
  #pragma unroll
  for (int i = 0; i < 4; ++i) {
    int c = tid + 256 * i;
    h[(size_t)row * DM + c] = f2bf((v[i] - mean) * inv * w[c] + bsh[c]);
  }
}

// ---------------- causal depthwise conv (k=4) + bias + silu ----------------
__global__ void conv_silu_k(const float* __restrict__ xz, const float* __restrict__ cw,
                            const float* __restrict__ cb, float* __restrict__ u) {
  int idx = blockIdx.x * 256 + threadIdx.x;
  if (idx >= BATCH * LSEQ * DI) return;
  int d = idx & (DI - 1);
  int bl = idx >> 11;
  int l = bl % LSEQ, b = bl / LSEQ;
  float acc = cb[d];
  const float* base = xz + (size_t)b * LSEQ * 4096 + d;
  #pragma unroll
  for (int k = 0; k < 4; ++k) {
    int ll = l - 3 + k;
    if (ll >= 0) acc += base[(size_t)ll * 4096] * cw[d * 4 + k];
  }
  u[idx] = acc / (1.f + __expf(-acc));
}

// ---------------- chunked selective scan ----------------
// pass 1: per (b,d,chunk) compute Aprod[s], h_end[s] (h0=0)
__global__ __launch_bounds__(256) void scan1_k(
    const float* __restrict__ dt, const float* __restrict__ u,
    const float* __restrict__ dbl, const float* __restrict__ alog,
    float* __restrict__ Ap, float* __restrict__ He)
{
  int d = blockIdx.x * 256 + threadIdx.x;
  int b = blockIdx.y, c = blockIdx.z;
  int t0 = c * LC, t1 = t0 + LC; if (t1 > LSEQ) t1 = LSEQ;
  float Ad[DSTATE], ap[DSTATE], h[DSTATE];
  #pragma unroll
  for (int s = 0; s < DSTATE; ++s) {
    Ad[s] = -__expf(alog[d * DSTATE + s]); ap[s] = 1.f; h[s] = 0.f;
  }
  const float* dblb = dbl + (size_t)b * LSEQ * 96;
  for (int t = t0; t < t1; ++t) {
    size_t ro = (size_t)b * LSEQ + t;
    float dtv = dt[ro * DI + d];
    float du = dtv * u[ro * DI + d];
    const float* r = dblb + (size_t)t * 96;
    #pragma unroll
    for (int s = 0; s < DSTATE; ++s) {
      float e = __expf(dtv * Ad[s]);
      h[s] = e * h[s] + du * r[64 + s];
      ap[s] *= e;
    }
  }
  size_t o = (((size_t)(b * NC + c)) * DI + d) * DSTATE;
  #pragma unroll
  for (int s = 0; s < DSTATE; ++s) { Ap[o + s] = ap[s]; He[o + s] = h[s]; }
}

// pass 2: sequential combine across chunks -> per-chunk initial state H0
__global__ __launch_bounds__(256) void scan2_k(
    const float* __restrict__ Ap, const float* __restrict__ He, float* __restrict__ H0)
{
  int d = blockIdx.x * 256 + threadIdx.x;
  int b = blockIdx.y;
  float h[DSTATE];
  #pragma unroll
  for (int s = 0; s < DSTATE; ++s) h[s] = 0.f;
  for (int c = 0; c < NC; ++c) {
    size_t o = (((size_t)(b * NC + c)) * DI + d) * DSTATE;
    #pragma unroll
    for (int s = 0; s < DSTATE; ++s) {
      H0[o + s] = h[s];
      h[s] = Ap[o + s] * h[s] + He[o + s];
    }
  }
}

// pass 3: re-scan chunk with correct h0, compute y (+D skip, silu(z) gate) -> bf16
__global__ __launch_bounds__(256) void scan3_k(
    const float* __restrict__ dt, const float* __restrict__ u,
    const float* __restrict__ dbl, const float* __restrict__ xz,
    const float* __restrict__ alog, const float* __restrict__ dsk,
    const float* __restrict__ H0, ushort* __restrict__ y)
{
  int d = blockIdx.x * 256 + threadIdx.x;
  int b = blockIdx.y, c = blockIdx.z;
  int t0 = c * LC, t1 = t0 + LC; if (t1 > LSEQ) t1 = LSEQ;
  float Ad[DSTATE], h[DSTATE];
  size_t o = (((size_t)(b * NC + c)) * DI + d) * DSTATE;
  #pragma unroll
  for (int s = 0; s < DSTATE; ++s) {
    Ad[s] = -__expf(alog[d * DSTATE + s]);
    h[s] = H0[o + s];
  }
  float Dv = dsk[d];
  const float* dblb = dbl + (size_t)b * LSEQ * 96;
  for (int t = t0; t < t1; ++t) {
    size_t ro = (size_t)b * LSEQ + t;
    float dtv = dt[ro * DI + d];
    float uv = u[ro * DI + d];
    float du = dtv * uv;
    const float* r = dblb + (size_t)t * 96;
    float yv = 0.f;
    #pragma unroll
    for (int s = 0; s < DSTATE; ++s) {
      h[s] = __expf(dtv * Ad[s]) * h[s] + du * r[64 + s];
      yv += h[s] * r[80 + s];
    }
    float z = xz[ro * 4096 + DI + d];
    y[ro * DI + d] = f2bf((yv + Dv * uv) * (z / (1.f + __expf(-z))));
  }
}

extern "C" void kernel_launch(void* const* d_in, const int* in_sizes, int n_in,
                              void* d_out, int out_size, void* d_ws, size_t ws_size,
                              hipStream_t stream) {
  const float* x         = (const float*)d_in[0];
  const float* patch_w   = (const float*)d_in[1];
  const float* patch_b   = (const float*)d_in[2];
  const float* cls_token = (const float*)d_in[3];
  const float* pos_embed = (const float*)d_in[4];
  const float* ln_w      = (const float*)d_in[5];
  const float* ln_b      = (const float*)d_in[6];
  const float* in_proj_w = (const float*)d_in[7];
  const float* conv_w    = (const float*)d_in[8];
  const float* conv_b    = (const float*)d_in[9];
  const float* x_proj_w  = (const float*)d_in[10];
  const float* dt_proj_w = (const float*)d_in[11];
  const float* dt_proj_b = (const float*)d_in[12];
  const float* A_log     = (const float*)d_in[13];
  const float* D_skip    = (const float*)d_in[14];
  const float* out_proj_w= (const float*)d_in[15];
  float* tok = (float*)d_out;

  char* base = (char*)d_ws;
  float*  xz_buf  = (float*)(base);                 // 1154*4096 f32  = 18,907,136 B
  float*  u_buf   = (float*)(base + 18907136);      // 1154*2048 f32  =  9,453,568 B
  float*  dbl_buf = (float*)(base + 28360704);      // 1154*96  f32   =    443,136 B
  float*  dt_buf  = (float*)(base + 28803840);      // 1154*2048 f32  =  9,453,568 B
  ushort* h_bf    = (ushort*)(base + 38257408);     // 1154*1024 u16  =  2,363,392 B
  ushort* y_bf    = (ushort*)(base + 40620800);     // 1154*2048 u16  =  4,726,784 B
  ushort* wbf     = (ushort*)(base + 45347584);     // 4096*1024 u16  =  8,388,608 B
  ushort* wbf2    = (ushort*)(base + 53736192);     // 1024*2048 u16  =  4,194,304 B
  float*  Ap      = (float*)(base + 57930496);      // 2*16*2048*16   =  4,194,304 B
  float*  He      = (float*)(base + 62124800);      //                =  4,194,304 B
  float*  H0      = (float*)(base + 66319104);      //                =  4,194,304 B
  float*  patches = xz_buf;  // 1152*768 f32, consumed before layer loop

  // ---- patch embed + pos ----
  im2col_k<<<(BATCH * NP * 768 + 255) / 256, 256, 0, stream>>>(x, patches);
  {
    dim3 gp(DM / GBN, (BATCH * NP + GBM - 1) / GBM);
    gemm_nt<<<gp, 256, 0, stream>>>(patches, 768, patch_w, tok,
                                    BATCH * NP, DM, 768, 3, patch_b, pos_embed);
  }
  cls_k<<<(DM + 255) / 256, 256, 0, stream>>>(cls_token, pos_embed, tok);

  // ---- 24 mamba layers ----
  for (int l = 0; l < NLAYERS; ++l) {
    ln_k<<<MROWS, 256, 0, stream>>>(tok, ln_w + l * DM, ln_b + l * DM, h_bf);

    f2bf_k<<<(2 * DI * DM) / 4 / 256, 256, 0, stream>>>(
        in_proj_w + (size_t)l * 2 * DI * DM, wbf, 2 * DI * DM);
    {
      dim3 g1(2 * DI / 64, (MROWS + 63) / 64);
      gemm_bf16<<<g1, 256, 0, stream>>>(h_bf, wbf, xz_buf, MROWS, 2 * DI, DM, 0);
    }

    conv_silu_k<<<(BATCH * LSEQ * DI + 255) / 256, 256, 0, stream>>>(
        xz_buf, conv_w + (size_t)l * DI * DCONV, conv_b + (size_t)l * DI, u_buf);

    {
      dim3 g2((96 + GBN - 1) / GBN, (MROWS + GBM - 1) / GBM);
      gemm_nt<<<g2, 256, 0, stream>>>(u_buf, DI, x_proj_w + (size_t)l * 96 * DI,
                                      dbl_buf, MROWS, 96, DI, 0, nullptr, nullptr);
    }
    {
      dim3 g3(DI / GBN, (MROWS + GBM - 1) / GBM);
      gemm_nt<<<g3, 256, 0, stream>>>(dbl_buf, 96, dt_proj_w + (size_t)l * DI * DTR,
                                      dt_buf, MROWS, DI, DTR, 2, dt_proj_b + (size_t)l * DI, nullptr);
    }

    {
      dim3 gs(DI / 256, BATCH, NC);
      scan1_k<<<gs, 256, 0, stream>>>(dt_buf, u_buf, dbl_buf,
                                      A_log + (size_t)l * DI * DSTATE, Ap, He);
      dim3 gs2(DI / 256, BATCH);
      scan2_k<<<gs2, 256, 0, stream>>>(Ap, He, H0);
      scan3_k<<<gs, 256, 0, stream>>>(dt_buf, u_buf, dbl_buf, xz_buf,
                                      A_log + (size_t)l * DI * DSTATE, D_skip + (size_t)l * DI,
                                      H0, y_bf);
    }

    f2bf_k<<<(DM * DI) / 4 / 256, 256, 0, stream>>>(
        out_proj_w + (size_t)l * DM * DI, wbf2, DM * DI);
    {
      dim3 g4(DM / 64, (MROWS + 63) / 64);
      gemm_bf16<<<g4, 256, 0, stream>>>(y_bf, wbf2, tok, MROWS, DM, DI, 1);
    }
  }
}

// Round 3
// 4456.082 us; speedup vs baseline: 4.2338x; 1.5377x over previous
//
#include <hip/hip_runtime.h>
#include <hip/hip_bf16.h>
#include <math.h>

#define BATCH 2
#define LSEQ 577
#define DM 1024
#define DI 2048
#define DSTATE 16
#define DCONV 4
#define DTR 64
#define NLAYERS 24
#define NP 576
#define MROWS (BATCH*LSEQ)   // 1154
#define NC 16
#define LC 37                // ceil(577/16)

typedef __attribute__((ext_vector_type(8))) short short8v;
typedef __attribute__((ext_vector_type(4))) float f32x4;

__device__ __forceinline__ ushort f2bf(float f) {
  unsigned int b = __float_as_uint(f);
  unsigned int r = (b + 0x7FFFu + ((b >> 16) & 1u)) >> 16;
  return (ushort)r;
}

__device__ __forceinline__ void gload16(const void* g, void* l) {
  __builtin_amdgcn_global_load_lds(
      (const __attribute__((address_space(1))) unsigned int*)g,
      (__attribute__((address_space(3))) unsigned int*)l, 16, 0, 0);
}

// ---------------- fp32 -> bf16 conversion (RNE), 4 elems/thread ----------------
__global__ void f2bf_k(const float* __restrict__ in, ushort* __restrict__ out, int n) {
  int i = (blockIdx.x * 256 + threadIdx.x) * 4;
  if (i >= n) return;
  float4 v = *(const float4*)(in + i);
  ushort4 o;
  o.x = f2bf(v.x); o.y = f2bf(v.y); o.z = f2bf(v.z); o.w = f2bf(v.w);
  *(ushort4*)(out + i) = o;
}

// ======================= 128x128 bf16 MFMA GEMM =======================
// C(M,N) fp32 = A(M,K)bf16 * W(N,K)^T bf16.  8 waves (512 thr), BK=64.
// LDS: A[128][128B] at 0, B at 16384. Linear dest (global_load_lds),
// XOR swizzle (row&7)<<4 applied on pre-swizzled global source + reads.
__global__ __launch_bounds__(512) void gemm128(
    const ushort* __restrict__ A, const ushort* __restrict__ W,
    float* __restrict__ C, int M, int N, int K, int accum)
{
  __shared__ char lds[32768];
  int tid = threadIdx.x;
  int lane = tid & 63, w = tid >> 6;
  int bm = blockIdx.y * 128, bn = blockIdx.x * 128;

  int srow = tid >> 3;                       // 0..63
  int scol = ((tid & 7) ^ (srow & 7)) << 3;  // pre-swizzled source elem offset
  int ra0 = bm + srow;       if (ra0 > M - 1) ra0 = M - 1;
  int ra1 = bm + 64 + srow;  if (ra1 > M - 1) ra1 = M - 1;
  const ushort* ga0 = A + (size_t)ra0 * K + scol;
  const ushort* ga1 = A + (size_t)ra1 * K + scol;
  const ushort* gb0 = W + (size_t)(bn + srow) * K + scol;
  const ushort* gb1 = W + (size_t)(bn + 64 + srow) * K + scol;
  char* la0 = lds + (w << 10);
  char* la1 = lds + 8192 + (w << 10);
  char* lb0 = lds + 16384 + (w << 10);
  char* lb1 = lds + 24576 + (w << 10);

  int wr = w >> 2, wc = w & 3;               // wave tile: rows wr*64, cols wc*32
  int fr = lane & 15;
  int fsw = (fr & 7) << 4;
  int fk = (lane >> 4) << 4;

  f32x4 acc[4][2];
  #pragma unroll
  for (int m = 0; m < 4; ++m)
    #pragma unroll
    for (int n = 0; n < 2; ++n) acc[m][n] = (f32x4){0.f, 0.f, 0.f, 0.f};

  for (int k0 = 0; k0 < K; k0 += 64) {
    gload16(ga0 + k0, la0);
    gload16(ga1 + k0, la1);
    gload16(gb0 + k0, lb0);
    gload16(gb1 + k0, lb1);
    __syncthreads();
    #pragma unroll
    for (int ks = 0; ks < 2; ++ks) {
      int cb = (ks * 64 + fk) ^ fsw;
      short8v af[4], bf[2];
      #pragma unroll
      for (int m = 0; m < 4; ++m)
        af[m] = *(const short8v*)(lds + (wr * 64 + m * 16 + fr) * 128 + cb);
      #pragma unroll
      for (int n = 0; n < 2; ++n)
        bf[n] = *(const short8v*)(lds + 16384 + (wc * 32 + n * 16 + fr) * 128 + cb);
      #pragma unroll
      for (int m = 0; m < 4; ++m)
        #pragma unroll
        for (int n = 0; n < 2; ++n)
          acc[m][n] = __builtin_amdgcn_mfma_f32_16x16x32_bf16(af[m], bf[n], acc[m][n], 0, 0, 0);
    }
    __syncthreads();
  }

  #pragma unroll
  for (int m = 0; m < 4; ++m) {
    int rb = bm + wr * 64 + m * 16 + ((lane >> 4) << 2);
    #pragma unroll
    for (int j = 0; j < 4; ++j) {
      int r = rb + j;
      if (r >= M) break;
      float* cr = C + (size_t)r * N + bn + wc * 32 + fr;
      if (accum) { cr[0] += acc[m][0][j]; cr[16] += acc[m][1][j]; }
      else       { cr[0]  = acc[m][0][j]; cr[16]  = acc[m][1][j]; }
    }
  }
}

// ======================= x_proj split-K MFMA =======================
// dbl(M,96) += u_bf(M,2048) * xpw(96,2048)^T ; split K into 8, atomicAdd.
// 4 waves, BM=64, BN=96, BK=64. LDS: A 8KB at 0, B 12KB at 8192.
__global__ __launch_bounds__(256) void xproj_k(
    const ushort* __restrict__ A, const ushort* __restrict__ W,
    float* __restrict__ C, int M)
{
  __shared__ char lds[20480];
  int tid = threadIdx.x;
  int lane = tid & 63, w = tid >> 6;
  int bm = blockIdx.y * 64;
  int kbase = blockIdx.x * 256;              // 8 splits x 256

  int srow = tid >> 3;                       // 0..31
  int scol = ((tid & 7) ^ (srow & 7)) << 3;
  int ra0 = bm + srow;       if (ra0 > M - 1) ra0 = M - 1;
  int ra1 = bm + 32 + srow;  if (ra1 > M - 1) ra1 = M - 1;
  const ushort* ga0 = A + (size_t)ra0 * DI + kbase + scol;
  const ushort* ga1 = A + (size_t)ra1 * DI + kbase + scol;
  const ushort* gb0 = W + (size_t)(srow)      * DI + kbase + scol;
  const ushort* gb1 = W + (size_t)(srow + 32) * DI + kbase + scol;
  const ushort* gb2 = W + (size_t)(srow + 64) * DI + kbase + scol;
  char* la0 = lds + (w << 10);
  char* la1 = lds + 4096 + (w << 10);
  char* lb0 = lds + 8192 + (w << 10);
  char* lb1 = lds + 12288 + (w << 10);
  char* lb2 = lds + 16384 + (w << 10);

  int fr = lane & 15;
  int fsw = (fr & 7) << 4;
  int fk = (lane >> 4) << 4;
  int arow = (w * 16 + fr) * 128;

  f32x4 acc[6];
  #pragma unroll
  for (int n = 0; n < 6; ++n) acc[n] = (f32x4){0.f, 0.f, 0.f, 0.f};

  for (int k0 = 0; k0 < 256; k0 += 64) {
    gload16(ga0 + k0, la0);
    gload16(ga1 + k0, la1);
    gload16(gb0 + k0, lb0);
    gload16(gb1 + k0, lb1);
    gload16(gb2 + k0, lb2);
    __syncthreads();
    #pragma unroll
    for (int ks = 0; ks < 2; ++ks) {
      int cb = (ks * 64 + fk) ^ fsw;
      short8v af = *(const short8v*)(lds + arow + cb);
      #pragma unroll
      for (int n = 0; n < 6; ++n) {
        short8v bf = *(const short8v*)(lds + 8192 + (n * 16 + fr) * 128 + cb);
        acc[n] = __builtin_amdgcn_mfma_f32_16x16x32_bf16(af, bf, acc[n], 0, 0, 0);
      }
    }
    __syncthreads();
  }

  int rb = bm + w * 16 + ((lane >> 4) << 2);
  #pragma unroll
  for (int j = 0; j < 4; ++j) {
    int r = rb + j;
    if (r >= M) break;
    #pragma unroll
    for (int n = 0; n < 6; ++n)
      atomicAdd(C + (size_t)r * 96 + n * 16 + fr, acc[n][j]);
  }
}

// ---------------- im2col for patch embedding ----------------
__global__ void im2col_k(const float* __restrict__ x, float* __restrict__ patches) {
  int idx = blockIdx.x * 256 + threadIdx.x;
  if (idx >= BATCH * NP * 768) return;
  int col = idx % 768, row = idx / 768;
  int b = row / NP, p = row % NP;
  int ph = p / 24, pw = p % 24;
  int c = col >> 8, r = col & 255, kh = r >> 4, kw = r & 15;
  patches[idx] = x[(((size_t)(b * 3 + c) * 384) + ph * 16 + kh) * 384 + pw * 16 + kw];
}

// ---------------- generic fp32 GEMM (patch embed + dt_proj) ----------------
#define GBM 64
#define GBN 64
#define GBK 16

__global__ __launch_bounds__(256) void gemm_nt(
    const float* __restrict__ A, int lda,
    const float* __restrict__ Bw,
    float* __restrict__ C,
    int M, int N, int K, int mode,
    const float* __restrict__ bias, const float* __restrict__ pos)
{
  __shared__ float As[GBK][GBM];
  __shared__ float Bs[GBK][GBN];
  int tid = threadIdx.x;
  int bm = blockIdx.y * GBM, bn = blockIdx.x * GBN;
  int lrow = tid >> 2, lk = (tid & 3) << 2;
  int tm = (tid >> 4) << 2, tn = (tid & 15) << 2;
  float acc[4][4] = {};
  for (int k0 = 0; k0 < K; k0 += GBK) {
    float4 va = make_float4(0.f, 0.f, 0.f, 0.f);
    float4 vb = make_float4(0.f, 0.f, 0.f, 0.f);
    if (bm + lrow < M) va = *(const float4*)(A + (size_t)(bm + lrow) * lda + k0 + lk);
    if (bn + lrow < N) vb = *(const float4*)(Bw + (size_t)(bn + lrow) * K + k0 + lk);
    As[lk + 0][lrow] = va.x; As[lk + 1][lrow] = va.y; As[lk + 2][lrow] = va.z; As[lk + 3][lrow] = va.w;
    Bs[lk + 0][lrow] = vb.x; Bs[lk + 1][lrow] = vb.y; Bs[lk + 2][lrow] = vb.z; Bs[lk + 3][lrow] = vb.w;
    __syncthreads();
    #pragma unroll
    for (int k = 0; k < GBK; ++k) {
      float4 a4 = *(const float4*)&As[k][tm];
      float4 b4 = *(const float4*)&Bs[k][tn];
      float av[4] = {a4.x, a4.y, a4.z, a4.w};
      float bv[4] = {b4.x, b4.y, b4.z, b4.w};
      #pragma unroll
      for (int i = 0; i < 4; ++i)
        #pragma unroll
        for (int j = 0; j < 4; ++j) acc[i][j] += av[i] * bv[j];
    }
    __syncthreads();
  }
  #pragma unroll
  for (int i = 0; i < 4; ++i) {
    int m = bm + tm + i;
    if (m >= M) break;
    #pragma unroll
    for (int j = 0; j < 4; ++j) {
      int n = bn + tn + j;
      if (n >= N) continue;
      float v = acc[i][j];
      if (mode == 0) {
        C[(size_t)m * N + n] = v;
      } else if (mode == 2) {
        float t = v + bias[n];
        C[(size_t)m * N + n] = (t > 20.f) ? t : log1pf(__expf(t));
      } else {
        int b = m / NP, p = m % NP;
        size_t orow = (size_t)(b * LSEQ + 1 + p);
        C[orow * DM + n] = v + bias[n] + pos[(size_t)(1 + p) * DM + n];
      }
    }
  }
}

// ---------------- cls token row ----------------
__global__ void cls_k(const float* __restrict__ cls, const float* __restrict__ pos,
                      float* __restrict__ out) {
  int n = blockIdx.x * 256 + threadIdx.x;
  if (n >= DM) return;
  float v = cls[n] + pos[n];
  out[n] = v;
  out[(size_t)LSEQ * DM + n] = v;
}

// ---------------- LayerNorm -> bf16 ----------------
__global__ __launch_bounds__(256) void ln_k(const float* __restrict__ tok,
    const float* __restrict__ w, const float* __restrict__ bsh,
    ushort* __restrict__ h) {
  int row = blockIdx.x;
  const float* xr = tok + (size_t)row * DM;
  int tid = threadIdx.x;
  float v[4];
  #pragma unroll
  for (int i = 0; i < 4; ++i) v[i] = xr[tid + 256 * i];
  float s = v[0] + v[1] + v[2] + v[3];
  float s2 = v[0] * v[0] + v[1] * v[1] + v[2] * v[2] + v[3] * v[3];
  #pragma unroll
  for (int off = 32; off; off >>= 1) { s += __shfl_xor(s, off); s2 += __shfl_xor(s2, off); }
  __shared__ float ps[4], ps2[4];
  if ((tid & 63) == 0) { ps[tid >> 6] = s; ps2[tid >> 6] = s2; }
  __syncthreads();
  s = ps[0] + ps[1] + ps[2] + ps[3];
  s2 = ps2[0] + ps2[1] + ps2[2] + ps2[3];
  float mean = s * (1.f / DM);
  float var = s2 * (1.f / DM) - mean * mean;
  float inv = rsqrtf(var + 1e-5f);
  #pragma unroll
  for (int i = 0; i < 4; ++i) {
    int c = tid + 256 * i;
    h[(size_t)row * DM + c] = f2bf((v[i] - mean) * inv * w[c] + bsh[c]);
  }
}

// ---------------- causal depthwise conv (k=4) + bias + silu (fp32 + bf16 out) ----------------
__global__ void conv_silu_k(const float* __restrict__ xz, const float* __restrict__ cw,
                            const float* __restrict__ cb, float* __restrict__ u,
                            ushort* __restrict__ ubf) {
  int idx = blockIdx.x * 256 + threadIdx.x;
  if (idx >= BATCH * LSEQ * DI) return;
  int d = idx & (DI - 1);
  int bl = idx >> 11;
  int l = bl % LSEQ, b = bl / LSEQ;
  float acc = cb[d];
  const float* base = xz + (size_t)b * LSEQ * 4096 + d;
  #pragma unroll
  for (int k = 0; k < 4; ++k) {
    int ll = l - 3 + k;
    if (ll >= 0) acc += base[(size_t)ll * 4096] * cw[d * 4 + k];
  }
  float val = acc / (1.f + __expf(-acc));
  u[idx] = val;
  ubf[idx] = f2bf(val);
}

// ---------------- chunked selective scan ----------------
__global__ __launch_bounds__(256) void scan1_k(
    const float* __restrict__ dt, const float* __restrict__ u,
    const float* __restrict__ dbl, const float* __restrict__ alog,
    float* __restrict__ Ap, float* __restrict__ He)
{
  int d = blockIdx.x * 256 + threadIdx.x;
  int b = blockIdx.y, c = blockIdx.z;
  int t0 = c * LC, t1 = t0 + LC; if (t1 > LSEQ) t1 = LSEQ;
  float Ad[DSTATE], ap[DSTATE], h[DSTATE];
  #pragma unroll
  for (int s = 0; s < DSTATE; ++s) {
    Ad[s] = -__expf(alog[d * DSTATE + s]); ap[s] = 1.f; h[s] = 0.f;
  }
  const float* dblb = dbl + (size_t)b * LSEQ * 96;
  for (int t = t0; t < t1; ++t) {
    size_t ro = (size_t)b * LSEQ + t;
    float dtv = dt[ro * DI + d];
    float du = dtv * u[ro * DI + d];
    const float* r = dblb + (size_t)t * 96;
    #pragma unroll
    for (int s = 0; s < DSTATE; ++s) {
      float e = __expf(dtv * Ad[s]);
      h[s] = e * h[s] + du * r[64 + s];
      ap[s] *= e;
    }
  }
  size_t o = (((size_t)(b * NC + c)) * DI + d) * DSTATE;
  #pragma unroll
  for (int s = 0; s < DSTATE; ++s) { Ap[o + s] = ap[s]; He[o + s] = h[s]; }
}

// pass 2: sequential combine; H0 written IN PLACE into Ap
__global__ __launch_bounds__(256) void scan2_k(
    float* __restrict__ Ap, const float* __restrict__ He)
{
  int d = blockIdx.x * 256 + threadIdx.x;
  int b = blockIdx.y;
  float h[DSTATE];
  #pragma unroll
  for (int s = 0; s < DSTATE; ++s) h[s] = 0.f;
  for (int c = 0; c < NC; ++c) {
    size_t o = (((size_t)(b * NC + c)) * DI + d) * DSTATE;
    #pragma unroll
    for (int s = 0; s < DSTATE; ++s) {
      float ap = Ap[o + s], he = He[o + s];
      Ap[o + s] = h[s];
      h[s] = ap * h[s] + he;
    }
  }
}

// pass 3: re-scan chunk with h0 (from Ap buffer), write gated y -> bf16
__global__ __launch_bounds__(256) void scan3_k(
    const float* __restrict__ dt, const float* __restrict__ u,
    const float* __restrict__ dbl, const float* __restrict__ xz,
    const float* __restrict__ alog, const float* __restrict__ dsk,
    const float* __restrict__ H0, ushort* __restrict__ y)
{
  int d = blockIdx.x * 256 + threadIdx.x;
  int b = blockIdx.y, c = blockIdx.z;
  int t0 = c * LC, t1 = t0 + LC; if (t1 > LSEQ) t1 = LSEQ;
  float Ad[DSTATE], h[DSTATE];
  size_t o = (((size_t)(b * NC + c)) * DI + d) * DSTATE;
  #pragma unroll
  for (int s = 0; s < DSTATE; ++s) {
    Ad[s] = -__expf(alog[d * DSTATE + s]);
    h[s] = H0[o + s];
  }
  float Dv = dsk[d];
  const float* dblb = dbl + (size_t)b * LSEQ * 96;
  for (int t = t0; t < t1; ++t) {
    size_t ro = (size_t)b * LSEQ + t;
    float dtv = dt[ro * DI + d];
    float uv = u[ro * DI + d];
    float du = dtv * uv;
    const float* r = dblb + (size_t)t * 96;
    float yv = 0.f;
    #pragma unroll
    for (int s = 0; s < DSTATE; ++s) {
      h[s] = __expf(dtv * Ad[s]) * h[s] + du * r[64 + s];
      yv += h[s] * r[80 + s];
    }
    float z = xz[ro * 4096 + DI + d];
    y[ro * DI + d] = f2bf((yv + Dv * uv) * (z / (1.f + __expf(-z))));
  }
}

extern "C" void kernel_launch(void* const* d_in, const int* in_sizes, int n_in,
                              void* d_out, int out_size, void* d_ws, size_t ws_size,
                              hipStream_t stream) {
  const float* x         = (const float*)d_in[0];
  const float* patch_w   = (const float*)d_in[1];
  const float* patch_b   = (const float*)d_in[2];
  const float* cls_token = (const float*)d_in[3];
  const float* pos_embed = (const float*)d_in[4];
  const float* ln_w      = (const float*)d_in[5];
  const float* ln_b      = (const float*)d_in[6];
  const float* in_proj_w = (const float*)d_in[7];
  const float* conv_w    = (const float*)d_in[8];
  const float* conv_b    = (const float*)d_in[9];
  const float* x_proj_w  = (const float*)d_in[10];
  const float* dt_proj_w = (const float*)d_in[11];
  const float* dt_proj_b = (const float*)d_in[12];
  const float* A_log     = (const float*)d_in[13];
  const float* D_skip    = (const float*)d_in[14];
  const float* out_proj_w= (const float*)d_in[15];
  float* tok = (float*)d_out;

  char* base = (char*)d_ws;
  float*  xz_buf  = (float*)(base);                 // 18,907,136
  float*  u_buf   = (float*)(base + 18907136);      //  9,453,568
  ushort* u_bf    = (ushort*)(base + 28360704);     //  4,726,784
  float*  dbl_buf = (float*)(base + 33087488);      //    443,136
  float*  dt_buf  = (float*)(base + 33530624);      //  9,453,568
  ushort* h_bf    = (ushort*)(base + 42984192);     //  2,363,392
  ushort* y_bf    = (ushort*)(base + 45347584);     //  4,726,784
  ushort* wbf     = (ushort*)(base + 50074368);     //  8,388,608 (in/out proj share)
  ushort* wxp     = (ushort*)(base + 58462976);     //    393,216
  float*  Ap      = (float*)(base + 58856192);      //  4,194,304 (becomes H0)
  float*  He      = (float*)(base + 63050496);      //  4,194,304  -> total 67.2MB
  float*  patches = xz_buf;

  // ---- patch embed + pos ----
  im2col_k<<<(BATCH * NP * 768 + 255) / 256, 256, 0, stream>>>(x, patches);
  {
    dim3 gp(DM / GBN, (BATCH * NP + GBM - 1) / GBM);
    gemm_nt<<<gp, 256, 0, stream>>>(patches, 768, patch_w, tok,
                                    BATCH * NP, DM, 768, 3, patch_b, pos_embed);
  }
  cls_k<<<(DM + 255) / 256, 256, 0, stream>>>(cls_token, pos_embed, tok);

  // ---- 24 mamba layers ----
  for (int l = 0; l < NLAYERS; ++l) {
    ln_k<<<MROWS, 256, 0, stream>>>(tok, ln_w + l * DM, ln_b + l * DM, h_bf);

    f2bf_k<<<(2 * DI * DM) / 4 / 256, 256, 0, stream>>>(
        in_proj_w + (size_t)l * 2 * DI * DM, wbf, 2 * DI * DM);
    {
      dim3 g1(2 * DI / 128, (MROWS + 127) / 128);
      gemm128<<<g1, 512, 0, stream>>>(h_bf, wbf, xz_buf, MROWS, 2 * DI, DM, 0);
    }

    conv_silu_k<<<(BATCH * LSEQ * DI + 255) / 256, 256, 0, stream>>>(
        xz_buf, conv_w + (size_t)l * DI * DCONV, conv_b + (size_t)l * DI, u_buf, u_bf);

    f2bf_k<<<(96 * DI) / 4 / 256, 256, 0, stream>>>(
        x_proj_w + (size_t)l * 96 * DI, wxp, 96 * DI);
    hipMemsetAsync(dbl_buf, 0, (size_t)MROWS * 96 * 4, stream);
    {
      dim3 g2(8, (MROWS + 63) / 64);   // 8 K-splits
      xproj_k<<<g2, 256, 0, stream>>>(u_bf, wxp, dbl_buf, MROWS);
    }

    {
      dim3 g3(DI / GBN, (MROWS + GBM - 1) / GBM);
      gemm_nt<<<g3, 256, 0, stream>>>(dbl_buf, 96, dt_proj_w + (size_t)l * DI * DTR,
                                      dt_buf, MROWS, DI, DTR, 2, dt_proj_b + (size_t)l * DI, nullptr);
    }

    {
      dim3 gs(DI / 256, BATCH, NC);
      scan1_k<<<gs, 256, 0, stream>>>(dt_buf, u_buf, dbl_buf,
                                      A_log + (size_t)l * DI * DSTATE, Ap, He);
      dim3 gs2(DI / 256, BATCH);
      scan2_k<<<gs2, 256, 0, stream>>>(Ap, He);
      scan3_k<<<gs, 256, 0, stream>>>(dt_buf, u_buf, dbl_buf, xz_buf,
                                      A_log + (size_t)l * DI * DSTATE, D_skip + (size_t)l * DI,
                                      Ap, y_bf);
    }

    f2bf_k<<<(DM * DI) / 4 / 256, 256, 0, stream>>>(
        out_proj_w + (size_t)l * DM * DI, wbf, DM * DI);
    {
      dim3 g4(DM / 128, (MROWS + 127) / 128);
      gemm128<<<g4, 512, 0, stream>>>(y_bf, wbf, tok, MROWS, DM, DI, 1);
    }
  }
}

// Round 4
// 4289.784 us; speedup vs baseline: 4.3980x; 1.0388x over previous
//
#include <hip/hip_runtime.h>
#include <hip/hip_bf16.h>
#include <math.h>

#define BATCH 2
#define LSEQ 577
#define DM 1024
#define DI 2048
#define DSTATE 16
#define DTR 64
#define NLAYERS 24
#define NP 576
#define MROWS 1154
#define NC 32
#define LC 19

typedef __attribute__((ext_vector_type(8))) short short8v;
typedef __attribute__((ext_vector_type(4))) float f32x4;

__device__ __forceinline__ ushort f2bf(float f) {
  unsigned int b = __float_as_uint(f);
  return (ushort)((b + 0x7FFFu + ((b >> 16) & 1u)) >> 16);
}
__device__ __forceinline__ float bf2f(ushort u) {
  return __uint_as_float(((unsigned int)u) << 16);
}
__device__ __forceinline__ void gload16(const void* g, void* l) {
  __builtin_amdgcn_global_load_lds(
      (const __attribute__((address_space(1))) unsigned int*)g,
      (__attribute__((address_space(3))) unsigned int*)l, 16, 0, 0);
}
__device__ __forceinline__ void cvt16(const float* g, char* ldsrow, int bb, int bswz) {
  float4 v0 = *(const float4*)(g);
  float4 v1 = *(const float4*)(g + 4);
  float4 v2 = *(const float4*)(g + 8);
  float4 v3 = *(const float4*)(g + 12);
  short8v c0 = {(short)f2bf(v0.x), (short)f2bf(v0.y), (short)f2bf(v0.z), (short)f2bf(v0.w),
                (short)f2bf(v1.x), (short)f2bf(v1.y), (short)f2bf(v1.z), (short)f2bf(v1.w)};
  short8v c1 = {(short)f2bf(v2.x), (short)f2bf(v2.y), (short)f2bf(v2.z), (short)f2bf(v2.w),
                (short)f2bf(v3.x), (short)f2bf(v3.y), (short)f2bf(v3.z), (short)f2bf(v3.w)};
  *(short8v*)(ldsrow + (bb ^ bswz)) = c0;
  *(short8v*)(ldsrow + ((bb + 16) ^ bswz)) = c1;
}

// ======================= unified 128x128 bf16 MFMA GEMM =======================
// C(M,N) = A(M,K) * W(N,K)^T.  A: bf16 (global_load_lds) or fp32 (reg-staged,
// AF32=1). W: fp32, reg-staged with in-register bf16 convert + swizzled ds_write.
// MODE 0: C=acc  1: C+=acc  2: C=softplus(acc+bias[n])
// MODE 3: patch scatter (+bias+pos)  4: n<DI -> C fp32 ; n>=DI -> zout bf16
template<int AF32, int MODE>
__global__ __launch_bounds__(512) void gemm_t(
    const void* __restrict__ Ap_, int lda,
    const float* __restrict__ Bw, int ldb,
    float* __restrict__ C, int ldc,
    int M, int N, int K,
    const float* __restrict__ bias, const float* __restrict__ pos,
    ushort* __restrict__ zout)
{
  __shared__ char lds[32768];
  int tid = threadIdx.x;
  int lane = tid & 63, w = tid >> 6;
  int bm = blockIdx.y * 128, bn = blockIdx.x * 128;

  // bf16-A staging (global_load_lds, pre-swizzled source)
  const ushort* Abf = (const ushort*)Ap_;
  int srow = tid >> 3;
  int scol = ((tid & 7) ^ (srow & 7)) << 3;
  int ra0 = bm + srow;      if (ra0 > M - 1) ra0 = M - 1;
  int ra1 = bm + 64 + srow; if (ra1 > M - 1) ra1 = M - 1;
  const ushort* ga0 = Abf + (size_t)ra0 * lda + scol;
  const ushort* ga1 = Abf + (size_t)ra1 * lda + scol;
  char* la0 = lds + (w << 10);
  char* la1 = lds + 8192 + (w << 10);

  // fp32 staging (B always; A if AF32): row = tid>>2 (0..127), 16 elems each
  int brow = tid >> 2;
  int be0 = (tid & 3) << 4;
  int bb = be0 << 1;
  int bswz = (brow & 7) << 4;
  const float* gB = Bw + (size_t)(bn + brow) * ldb + be0;
  char* ldsBrow = lds + 16384 + brow * 128;
  const float* gAf = nullptr;
  char* ldsArow = lds + brow * 128;
  if (AF32) {
    int raf = bm + brow; if (raf > M - 1) raf = M - 1;
    gAf = (const float*)Ap_ + (size_t)raf * lda + be0;
  }

  int wr = w >> 2, wc = w & 3;
  int fr = lane & 15;
  int fsw = (fr & 7) << 4;
  int fk = (lane >> 4) << 4;

  f32x4 acc[4][2];
  #pragma unroll
  for (int m = 0; m < 4; ++m)
    #pragma unroll
    for (int n = 0; n < 2; ++n) acc[m][n] = (f32x4){0.f, 0.f, 0.f, 0.f};

  for (int k0 = 0; k0 < K; k0 += 64) {
    if (!AF32) {
      gload16(ga0 + k0, la0);
      gload16(ga1 + k0, la1);
    } else {
      cvt16(gAf + k0, ldsArow, bb, bswz);
    }
    cvt16(gB + k0, ldsBrow, bb, bswz);
    __syncthreads();
    #pragma unroll
    for (int ks = 0; ks < 2; ++ks) {
      int cb = (ks * 64 + fk) ^ fsw;
      short8v af[4], bf[2];
      #pragma unroll
      for (int m = 0; m < 4; ++m)
        af[m] = *(const short8v*)(lds + (wr * 64 + m * 16 + fr) * 128 + cb);
      #pragma unroll
      for (int n = 0; n < 2; ++n)
        bf[n] = *(const short8v*)(lds + 16384 + (wc * 32 + n * 16 + fr) * 128 + cb);
      #pragma unroll
      for (int m = 0; m < 4; ++m)
        #pragma unroll
        for (int n = 0; n < 2; ++n)
          acc[m][n] = __builtin_amdgcn_mfma_f32_16x16x32_bf16(af[m], bf[n], acc[m][n], 0, 0, 0);
    }
    __syncthreads();
  }

  #pragma unroll
  for (int m = 0; m < 4; ++m) {
    int rb = bm + wr * 64 + m * 16 + ((lane >> 4) << 2);
    #pragma unroll
    for (int j = 0; j < 4; ++j) {
      int r = rb + j;
      if (r >= M) break;
      #pragma unroll
      for (int n2 = 0; n2 < 2; ++n2) {
        int n = bn + wc * 32 + n2 * 16 + fr;
        float v = acc[m][n2][j];
        if (MODE == 0) {
          C[(size_t)r * ldc + n] = v;
        } else if (MODE == 1) {
          C[(size_t)r * ldc + n] += v;
        } else if (MODE == 2) {
          float t = v + bias[n];
          C[(size_t)r * ldc + n] = (t > 20.f) ? t : log1pf(__expf(t));
        } else if (MODE == 3) {
          int b = r / NP, p = r % NP;
          C[((size_t)(b * LSEQ + 1 + p)) * ldc + n] = v + bias[n] + pos[(size_t)(1 + p) * ldc + n];
        } else {
          if (n < DI) C[(size_t)r * DI + n] = v;
          else        zout[(size_t)r * DI + n - DI] = f2bf(v);
        }
      }
    }
  }
}

// ======================= x_proj split-K MFMA (fp32 W reg-staged) =======================
__global__ __launch_bounds__(256) void xproj_k(
    const ushort* __restrict__ A, const float* __restrict__ W,
    float* __restrict__ C, int M)
{
  __shared__ char lds[20480];
  int tid = threadIdx.x;
  int lane = tid & 63, w = tid >> 6;
  int bm = blockIdx.y * 64;
  int kbase = blockIdx.x * 256;

  int srow = tid >> 3;
  int scol = ((tid & 7) ^ (srow & 7)) << 3;
  int ra0 = bm + srow;      if (ra0 > M - 1) ra0 = M - 1;
  int ra1 = bm + 32 + srow; if (ra1 > M - 1) ra1 = M - 1;
  const ushort* ga0 = A + (size_t)ra0 * DI + kbase + scol;
  const ushort* ga1 = A + (size_t)ra1 * DI + kbase + scol;
  char* la0 = lds + (w << 10);
  char* la1 = lds + 4096 + (w << 10);

  int fr = lane & 15;
  int fsw = (fr & 7) << 4;
  int fk = (lane >> 4) << 4;
  int arow = (w * 16 + fr) * 128;

  f32x4 acc[6];
  #pragma unroll
  for (int n = 0; n < 6; ++n) acc[n] = (f32x4){0.f, 0.f, 0.f, 0.f};

  for (int k0 = 0; k0 < 256; k0 += 64) {
    gload16(ga0 + k0, la0);
    gload16(ga1 + k0, la1);
    #pragma unroll
    for (int pass = 0; pass < 2; ++pass) {
      int slot = tid + pass * 256;
      if (slot < 384) {
        int row = slot >> 2, e0 = (slot & 3) << 4;
        cvt16(W + (size_t)row * DI + kbase + k0 + e0,
              lds + 8192 + row * 128, e0 << 1, (row & 7) << 4);
      }
    }
    __syncthreads();
    #pragma unroll
    for (int ks = 0; ks < 2; ++ks) {
      int cb = (ks * 64 + fk) ^ fsw;
      short8v af = *(const short8v*)(lds + arow + cb);
      #pragma unroll
      for (int n = 0; n < 6; ++n) {
        short8v bf = *(const short8v*)(lds + 8192 + (n * 16 + fr) * 128 + cb);
        acc[n] = __builtin_amdgcn_mfma_f32_16x16x32_bf16(af, bf, acc[n], 0, 0, 0);
      }
    }
    __syncthreads();
  }

  int rb = bm + w * 16 + ((lane >> 4) << 2);
  #pragma unroll
  for (int j = 0; j < 4; ++j) {
    int r = rb + j;
    if (r >= M) break;
    #pragma unroll
    for (int n = 0; n < 6; ++n)
      atomicAdd(C + (size_t)r * 96 + n * 16 + fr, acc[n][j]);
  }
}

// ---------------- im2col -> bf16 patches ----------------
__global__ void im2col_k(const float* __restrict__ x, ushort* __restrict__ patches) {
  int idx = blockIdx.x * 256 + threadIdx.x;
  if (idx >= BATCH * NP * 768) return;
  int col = idx % 768, row = idx / 768;
  int b = row / NP, p = row % NP;
  int ph = p / 24, pw = p % 24;
  int c = col >> 8, r = col & 255, kh = r >> 4, kw = r & 15;
  patches[idx] = f2bf(x[(((size_t)(b * 3 + c) * 384) + ph * 16 + kh) * 384 + pw * 16 + kw]);
}

// ---------------- cls token row ----------------
__global__ void cls_k(const float* __restrict__ cls, const float* __restrict__ pos,
                      float* __restrict__ out) {
  int n = blockIdx.x * 256 + threadIdx.x;
  if (n >= DM) return;
  float v = cls[n] + pos[n];
  out[n] = v;
  out[(size_t)LSEQ * DM + n] = v;
}

// ---------------- LayerNorm -> bf16 ----------------
__global__ __launch_bounds__(256) void ln_k(const float* __restrict__ tok,
    const float* __restrict__ w, const float* __restrict__ bsh,
    ushort* __restrict__ h) {
  int row = blockIdx.x;
  const float* xr = tok + (size_t)row * DM;
  int tid = threadIdx.x;
  float v[4];
  #pragma unroll
  for (int i = 0; i < 4; ++i) v[i] = xr[tid + 256 * i];
  float s = v[0] + v[1] + v[2] + v[3];
  float s2 = v[0] * v[0] + v[1] * v[1] + v[2] * v[2] + v[3] * v[3];
  #pragma unroll
  for (int off = 32; off; off >>= 1) { s += __shfl_xor(s, off); s2 += __shfl_xor(s2, off); }
  __shared__ float ps[4], ps2[4];
  if ((tid & 63) == 0) { ps[tid >> 6] = s; ps2[tid >> 6] = s2; }
  __syncthreads();
  s = ps[0] + ps[1] + ps[2] + ps[3];
  s2 = ps2[0] + ps2[1] + ps2[2] + ps2[3];
  float mean = s * (1.f / DM);
  float var = s2 * (1.f / DM) - mean * mean;
  float inv = rsqrtf(var + 1e-5f);
  #pragma unroll
  for (int i = 0; i < 4; ++i) {
    int c = tid + 256 * i;
    h[(size_t)row * DM + c] = f2bf((v[i] - mean) * inv * w[c] + bsh[c]);
  }
}

// ---------------- causal depthwise conv + silu -> bf16 (also zeroes dbl) ----------------
__global__ void conv_silu_k(const float* __restrict__ xc, const float* __restrict__ cw,
                            const float* __restrict__ cb, ushort* __restrict__ ubf,
                            float* __restrict__ dbl0) {
  int idx = blockIdx.x * 256 + threadIdx.x;
  if (idx < MROWS * 96) dbl0[idx] = 0.f;
  if (idx >= MROWS * DI) return;
  int d = idx & (DI - 1);
  int ro = idx >> 11;
  int l = ro % LSEQ;
  float acc = cb[d];
  #pragma unroll
  for (int k = 0; k < 4; ++k) {
    int ll = l - 3 + k;
    if (ll >= 0) acc += xc[(size_t)(ro - 3 + k) * DI + d] * cw[d * 4 + k];
  }
  ubf[idx] = f2bf(acc / (1.f + __expf(-acc)));
}

// ---------------- chunked selective scan ----------------
__global__ __launch_bounds__(256) void scan1_k(
    const float* __restrict__ dt, const ushort* __restrict__ ubf,
    const float* __restrict__ dbl, const float* __restrict__ alog,
    float* __restrict__ Ap, float* __restrict__ He)
{
  int d = blockIdx.x * 256 + threadIdx.x;
  int b = blockIdx.y, c = blockIdx.z;
  int t0 = c * LC, t1 = t0 + LC; if (t1 > LSEQ) t1 = LSEQ;
  float Ad[DSTATE], ap[DSTATE], h[DSTATE];
  #pragma unroll
  for (int s = 0; s < DSTATE; ++s) {
    Ad[s] = -__expf(alog[d * DSTATE + s]); ap[s] = 1.f; h[s] = 0.f;
  }
  for (int t = t0; t < t1; ++t) {
    size_t ro = (size_t)b * LSEQ + t;
    float dtv = dt[ro * DI + d];
    float du = dtv * bf2f(ubf[ro * DI + d]);
    const float* r = dbl + ro * 96;
    #pragma unroll
    for (int s = 0; s < DSTATE; ++s) {
      float e = __expf(dtv * Ad[s]);
      h[s] = e * h[s] + du * r[64 + s];
      ap[s] *= e;
    }
  }
  size_t o = (((size_t)(b * NC + c)) * DI + d) * DSTATE;
  #pragma unroll
  for (int s = 0; s < DSTATE; ++s) { Ap[o + s] = ap[s]; He[o + s] = h[s]; }
}

// pass 2: combine across chunks, parallel over (d,s); H0 in place into Ap
__global__ __launch_bounds__(256) void scan2_k(
    float* __restrict__ Ap, const float* __restrict__ He)
{
  int ds = blockIdx.x * 256 + threadIdx.x;        // d*16+s, 0..32767
  int b = blockIdx.y;
  float h = 0.f;
  for (int c = 0; c < NC; ++c) {
    size_t o = ((size_t)(b * NC + c)) * DI * DSTATE + ds;
    float ap = Ap[o], he = He[o];
    Ap[o] = h;
    h = ap * h + he;
  }
}

// pass 3: re-scan with h0, gated y -> bf16
__global__ __launch_bounds__(256) void scan3_k(
    const float* __restrict__ dt, const ushort* __restrict__ ubf,
    const float* __restrict__ dbl, const ushort* __restrict__ zbf,
    const float* __restrict__ alog, const float* __restrict__ dsk,
    const float* __restrict__ H0, ushort* __restrict__ y)
{
  int d = blockIdx.x * 256 + threadIdx.x;
  int b = blockIdx.y, c = blockIdx.z;
  int t0 = c * LC, t1 = t0 + LC; if (t1 > LSEQ) t1 = LSEQ;
  float Ad[DSTATE], h[DSTATE];
  size_t o = (((size_t)(b * NC + c)) * DI + d) * DSTATE;
  #pragma unroll
  for (int s = 0; s < DSTATE; ++s) {
    Ad[s] = -__expf(alog[d * DSTATE + s]);
    h[s] = H0[o + s];
  }
  float Dv = dsk[d];
  for (int t = t0; t < t1; ++t) {
    size_t ro = (size_t)b * LSEQ + t;
    float dtv = dt[ro * DI + d];
    float uv = bf2f(ubf[ro * DI + d]);
    float du = dtv * uv;
    const float* r = dbl + ro * 96;
    float yv = 0.f;
    #pragma unroll
    for (int s = 0; s < DSTATE; ++s) {
      h[s] = __expf(dtv * Ad[s]) * h[s] + du * r[64 + s];
      yv += h[s] * r[80 + s];
    }
    float z = bf2f(zbf[ro * DI + d]);
    y[ro * DI + d] = f2bf((yv + Dv * uv) * (z / (1.f + __expf(-z))));
  }
}

extern "C" void kernel_launch(void* const* d_in, const int* in_sizes, int n_in,
                              void* d_out, int out_size, void* d_ws, size_t ws_size,
                              hipStream_t stream) {
  const float* x         = (const float*)d_in[0];
  const float* patch_w   = (const float*)d_in[1];
  const float* patch_b   = (const float*)d_in[2];
  const float* cls_token = (const float*)d_in[3];
  const float* pos_embed = (const float*)d_in[4];
  const float* ln_w      = (const float*)d_in[5];
  const float* ln_b      = (const float*)d_in[6];
  const float* in_proj_w = (const float*)d_in[7];
  const float* conv_w    = (const float*)d_in[8];
  const float* conv_b    = (const float*)d_in[9];
  const float* x_proj_w  = (const float*)d_in[10];
  const float* dt_proj_w = (const float*)d_in[11];
  const float* dt_proj_b = (const float*)d_in[12];
  const float* A_log     = (const float*)d_in[13];
  const float* D_skip    = (const float*)d_in[14];
  const float* out_proj_w= (const float*)d_in[15];
  float* tok = (float*)d_out;

  char* base = (char*)d_ws;
  float*  xc_buf = (float*)(base);                  //  9,453,568
  ushort* z_bf   = (ushort*)(base + 9453568);       //  4,726,784
  ushort* u_bf   = (ushort*)(base + 14180352);      //  4,726,784
  float*  dbl    = (float*)(base + 18907136);       //    443,136
  float*  dt_buf = (float*)(base + 19350272);       //  9,453,568
  ushort* h_bf   = (ushort*)(base + 28803840);      //  2,363,392
  ushort* y_bf   = (ushort*)(base + 31167232);      //  4,726,784
  float*  Ap     = (float*)(base + 35894016);       //  8,388,608
  float*  He     = (float*)(base + 44282624);       //  8,388,608  (end ~52.7MB)
  ushort* patches= (ushort*)xc_buf;                 // alias, pre-layer only

  // ---- patch embed (bf16 MFMA) + pos ----
  im2col_k<<<(BATCH * NP * 768 + 255) / 256, 256, 0, stream>>>(x, patches);
  {
    dim3 gp(DM / 128, (BATCH * NP) / 128);
    gemm_t<0, 3><<<gp, 512, 0, stream>>>(patches, 768, patch_w, 768, tok, DM,
                                         BATCH * NP, DM, 768, patch_b, pos_embed, nullptr);
  }
  cls_k<<<(DM + 255) / 256, 256, 0, stream>>>(cls_token, pos_embed, tok);

  // ---- 24 mamba layers ----
  for (int l = 0; l < NLAYERS; ++l) {
    ln_k<<<MROWS, 256, 0, stream>>>(tok, ln_w + l * DM, ln_b + l * DM, h_bf);

    {
      dim3 g1(2 * DI / 128, (MROWS + 127) / 128);
      gemm_t<0, 4><<<g1, 512, 0, stream>>>(h_bf, DM, in_proj_w + (size_t)l * 2 * DI * DM, DM,
                                           xc_buf, DI, MROWS, 2 * DI, DM, nullptr, nullptr, z_bf);
    }

    conv_silu_k<<<(MROWS * DI + 255) / 256, 256, 0, stream>>>(
        xc_buf, conv_w + (size_t)l * DI * 4, conv_b + (size_t)l * DI, u_bf, dbl);

    {
      dim3 g2(8, (MROWS + 63) / 64);
      xproj_k<<<g2, 256, 0, stream>>>(u_bf, x_proj_w + (size_t)l * 96 * DI, dbl, MROWS);
    }

    {
      dim3 g3(DI / 128, (MROWS + 127) / 128);
      gemm_t<1, 2><<<g3, 512, 0, stream>>>(dbl, 96, dt_proj_w + (size_t)l * DI * DTR, DTR,
                                           dt_buf, DI, MROWS, DI, DTR,
                                           dt_proj_b + (size_t)l * DI, nullptr, nullptr);
    }

    {
      dim3 gs(DI / 256, BATCH, NC);
      scan1_k<<<gs, 256, 0, stream>>>(dt_buf, u_bf, dbl,
                                      A_log + (size_t)l * DI * DSTATE, Ap, He);
      dim3 gs2(DI * DSTATE / 256, BATCH);
      scan2_k<<<gs2, 256, 0, stream>>>(Ap, He);
      scan3_k<<<gs, 256, 0, stream>>>(dt_buf, u_bf, dbl, z_bf,
                                      A_log + (size_t)l * DI * DSTATE, D_skip + (size_t)l * DI,
                                      Ap, y_bf);
    }

    {
      dim3 g4(DM / 128, (MROWS + 127) / 128);
      gemm_t<0, 1><<<g4, 512, 0, stream>>>(y_bf, DI, out_proj_w + (size_t)l * DM * DI, DI,
                                           tok, DM, MROWS, DM, DI, nullptr, nullptr, nullptr);
    }
  }
}

// Round 5
// 3853.542 us; speedup vs baseline: 4.8959x; 1.1132x over previous
//
#include <hip/hip_runtime.h>
#include <hip/hip_bf16.h>
#include <math.h>

#define BATCH 2
#define LSEQ 577
#define DM 1024
#define DI 2048
#define DSTATE 16
#define DTR 64
#define NLAYERS 24
#define NP 576
#define MROWS 1154
#define NC 32
#define LC 19

typedef __attribute__((ext_vector_type(8))) short short8v;
typedef __attribute__((ext_vector_type(4))) float f32x4;

__device__ __forceinline__ ushort f2bf(float f) {
  unsigned int b = __float_as_uint(f);
  return (ushort)((b + 0x7FFFu + ((b >> 16) & 1u)) >> 16);
}
__device__ __forceinline__ float bf2f(ushort u) {
  return __uint_as_float(((unsigned int)u) << 16);
}
__device__ __forceinline__ void gload16(const void* g, void* l) {
  __builtin_amdgcn_global_load_lds(
      (const __attribute__((address_space(1))) unsigned int*)g,
      (__attribute__((address_space(3))) unsigned int*)l, 16, 0, 0);
}
__device__ __forceinline__ void cvt16(const float* g, char* ldsrow, int bb, int bswz) {
  float4 v0 = *(const float4*)(g);
  float4 v1 = *(const float4*)(g + 4);
  float4 v2 = *(const float4*)(g + 8);
  float4 v3 = *(const float4*)(g + 12);
  short8v c0 = {(short)f2bf(v0.x), (short)f2bf(v0.y), (short)f2bf(v0.z), (short)f2bf(v0.w),
                (short)f2bf(v1.x), (short)f2bf(v1.y), (short)f2bf(v1.z), (short)f2bf(v1.w)};
  short8v c1 = {(short)f2bf(v2.x), (short)f2bf(v2.y), (short)f2bf(v2.z), (short)f2bf(v2.w),
                (short)f2bf(v3.x), (short)f2bf(v3.y), (short)f2bf(v3.z), (short)f2bf(v3.w)};
  *(short8v*)(ldsrow + (bb ^ bswz)) = c0;
  *(short8v*)(ldsrow + ((bb + 16) ^ bswz)) = c1;
}

// ---------------- fp32 -> bf16, grid-stride ----------------
__global__ void f2bf_k(const float* __restrict__ in, ushort* __restrict__ out, int n) {
  for (int i = (blockIdx.x * 256 + threadIdx.x) * 4; i < n; i += gridDim.x * 1024) {
    float4 v = *(const float4*)(in + i);
    ushort4 o;
    o.x = f2bf(v.x); o.y = f2bf(v.y); o.z = f2bf(v.z); o.w = f2bf(v.w);
    *(ushort4*)(out + i) = o;
  }
}

// ======================= 128x128 bf16 MFMA GEMM (pure gload_lds) ===============
// C(M,N) = A(M,K) * W(N,K)^T, W bf16 precomputed. A bf16 (AF32=0) or fp32
// reg-staged+converted (AF32=1, dt GEMM only, K=64).
// MODE 0: C=v  1: C+=v  3: patch scatter(+bias+pos)
// MODE 4: n<DI -> C fp32 ; n>=DI -> out16 bf16 (in_proj xc/z split)
// MODE 5: out16 = bf16(softplus(v+bias[n])) (dt)
template<int AF32, int MODE>
__global__ __launch_bounds__(512) void gemm_b(
    const void* __restrict__ Ap_, int lda,
    const ushort* __restrict__ Bw, int ldb,
    float* __restrict__ C, int ldc,
    int M, int N, int K,
    const float* __restrict__ bias, const float* __restrict__ pos,
    ushort* __restrict__ out16)
{
  __shared__ char lds[32768];
  int tid = threadIdx.x;
  int lane = tid & 63, w = tid >> 6;
  int bm = blockIdx.y * 128, bn = blockIdx.x * 128;

  int srow = tid >> 3;                       // 0..63
  int scol = ((tid & 7) ^ (srow & 7)) << 3;  // pre-swizzled source col (elems)

  // B staging: bf16 gload_lds, rows bn+srow / bn+64+srow
  const ushort* gb0 = Bw + (size_t)(bn + srow) * ldb + scol;
  const ushort* gb1 = Bw + (size_t)(bn + 64 + srow) * ldb + scol;
  char* lb0 = lds + 16384 + (w << 10);
  char* lb1 = lds + 24576 + (w << 10);

  // A staging
  const ushort* ga0 = nullptr; const ushort* ga1 = nullptr;
  char* la0 = lds + (w << 10);
  char* la1 = lds + 8192 + (w << 10);
  const float* gAf = nullptr; char* ldsArow = nullptr; int bb = 0, bswz = 0;
  if (!AF32) {
    const ushort* Abf = (const ushort*)Ap_;
    int ra0 = bm + srow;      if (ra0 > M - 1) ra0 = M - 1;
    int ra1 = bm + 64 + srow; if (ra1 > M - 1) ra1 = M - 1;
    ga0 = Abf + (size_t)ra0 * lda + scol;
    ga1 = Abf + (size_t)ra1 * lda + scol;
  } else {
    int brow = tid >> 2;                    // 0..127
    int be0 = (tid & 3) << 4;
    bb = be0 << 1; bswz = (brow & 7) << 4;
    int raf = bm + brow; if (raf > M - 1) raf = M - 1;
    gAf = (const float*)Ap_ + (size_t)raf * lda + be0;
    ldsArow = lds + brow * 128;
  }

  int wr = w >> 2, wc = w & 3;
  int fr = lane & 15;
  int fsw = (fr & 7) << 4;
  int fk = (lane >> 4) << 4;

  f32x4 acc[4][2];
  #pragma unroll
  for (int m = 0; m < 4; ++m)
    #pragma unroll
    for (int n = 0; n < 2; ++n) acc[m][n] = (f32x4){0.f, 0.f, 0.f, 0.f};

  for (int k0 = 0; k0 < K; k0 += 64) {
    if (!AF32) {
      gload16(ga0 + k0, la0);
      gload16(ga1 + k0, la1);
    } else {
      cvt16(gAf + k0, ldsArow, bb, bswz);
    }
    gload16(gb0 + k0, lb0);
    gload16(gb1 + k0, lb1);
    __syncthreads();
    #pragma unroll
    for (int ks = 0; ks < 2; ++ks) {
      int cb = (ks * 64 + fk) ^ fsw;
      short8v af[4], bf[2];
      #pragma unroll
      for (int m = 0; m < 4; ++m)
        af[m] = *(const short8v*)(lds + (wr * 64 + m * 16 + fr) * 128 + cb);
      #pragma unroll
      for (int n = 0; n < 2; ++n)
        bf[n] = *(const short8v*)(lds + 16384 + (wc * 32 + n * 16 + fr) * 128 + cb);
      #pragma unroll
      for (int m = 0; m < 4; ++m)
        #pragma unroll
        for (int n = 0; n < 2; ++n)
          acc[m][n] = __builtin_amdgcn_mfma_f32_16x16x32_bf16(af[m], bf[n], acc[m][n], 0, 0, 0);
    }
    __syncthreads();
  }

  #pragma unroll
  for (int m = 0; m < 4; ++m) {
    int rb = bm + wr * 64 + m * 16 + ((lane >> 4) << 2);
    #pragma unroll
    for (int j = 0; j < 4; ++j) {
      int r = rb + j;
      if (r >= M) break;
      #pragma unroll
      for (int n2 = 0; n2 < 2; ++n2) {
        int n = bn + wc * 32 + n2 * 16 + fr;
        float v = acc[m][n2][j];
        if (MODE == 0) {
          C[(size_t)r * ldc + n] = v;
        } else if (MODE == 1) {
          C[(size_t)r * ldc + n] += v;
        } else if (MODE == 3) {
          int b = r / NP, p = r % NP;
          C[((size_t)(b * LSEQ + 1 + p)) * ldc + n] = v + bias[n] + pos[(size_t)(1 + p) * ldc + n];
        } else if (MODE == 4) {
          if (n < DI) C[(size_t)r * DI + n] = v;
          else        out16[(size_t)r * DI + n - DI] = f2bf(v);
        } else {  // 5: dt softplus -> bf16
          float t = v + bias[n];
          out16[(size_t)r * N + n] = f2bf((t > 20.f) ? t : log1pf(__expf(t)));
        }
      }
    }
  }
}

// ======================= x_proj split-K MFMA (bf16 W) =======================
__global__ __launch_bounds__(256) void xproj_k(
    const ushort* __restrict__ A, const ushort* __restrict__ W,
    float* __restrict__ C, int M)
{
  __shared__ char lds[20480];
  int tid = threadIdx.x;
  int lane = tid & 63, w = tid >> 6;
  int bm = blockIdx.y * 64;
  int kbase = blockIdx.x * 256;

  int srow = tid >> 3;
  int scol = ((tid & 7) ^ (srow & 7)) << 3;
  int ra0 = bm + srow;      if (ra0 > M - 1) ra0 = M - 1;
  int ra1 = bm + 32 + srow; if (ra1 > M - 1) ra1 = M - 1;
  const ushort* ga0 = A + (size_t)ra0 * DI + kbase + scol;
  const ushort* ga1 = A + (size_t)ra1 * DI + kbase + scol;
  char* la0 = lds + (w << 10);
  char* la1 = lds + 4096 + (w << 10);
  // B: 96 rows x 128B = 12KB, 3 gload rounds of 32 rows
  const ushort* gb0 = W + (size_t)(srow)      * DI + kbase + scol;
  const ushort* gb1 = W + (size_t)(srow + 32) * DI + kbase + scol;
  const ushort* gb2 = W + (size_t)(srow + 64) * DI + kbase + scol;
  char* lb0 = lds + 8192 + (w << 10);
  char* lb1 = lds + 12288 + (w << 10);
  char* lb2 = lds + 16384 + (w << 10);

  int fr = lane & 15;
  int fsw = (fr & 7) << 4;
  int fk = (lane >> 4) << 4;
  int arow = (w * 16 + fr) * 128;

  f32x4 acc[6];
  #pragma unroll
  for (int n = 0; n < 6; ++n) acc[n] = (f32x4){0.f, 0.f, 0.f, 0.f};

  for (int k0 = 0; k0 < 256; k0 += 64) {
    gload16(ga0 + k0, la0);
    gload16(ga1 + k0, la1);
    gload16(gb0 + k0, lb0);
    gload16(gb1 + k0, lb1);
    gload16(gb2 + k0, lb2);
    __syncthreads();
    #pragma unroll
    for (int ks = 0; ks < 2; ++ks) {
      int cb = (ks * 64 + fk) ^ fsw;
      short8v af = *(const short8v*)(lds + arow + cb);
      #pragma unroll
      for (int n = 0; n < 6; ++n) {
        short8v bf = *(const short8v*)(lds + 8192 + (n * 16 + fr) * 128 + cb);
        acc[n] = __builtin_amdgcn_mfma_f32_16x16x32_bf16(af, bf, acc[n], 0, 0, 0);
      }
    }
    __syncthreads();
  }

  int rb = bm + w * 16 + ((lane >> 4) << 2);
  #pragma unroll
  for (int j = 0; j < 4; ++j) {
    int r = rb + j;
    if (r >= M) break;
    #pragma unroll
    for (int n = 0; n < 6; ++n)
      atomicAdd(C + (size_t)r * 96 + n * 16 + fr, acc[n][j]);
  }
}

// ---------------- im2col -> bf16 patches ----------------
__global__ void im2col_k(const float* __restrict__ x, ushort* __restrict__ patches) {
  int idx = blockIdx.x * 256 + threadIdx.x;
  if (idx >= BATCH * NP * 768) return;
  int col = idx % 768, row = idx / 768;
  int b = row / NP, p = row % NP;
  int ph = p / 24, pw = p % 24;
  int c = col >> 8, r = col & 255, kh = r >> 4, kw = r & 15;
  patches[idx] = f2bf(x[(((size_t)(b * 3 + c) * 384) + ph * 16 + kh) * 384 + pw * 16 + kw]);
}

// ---------------- cls token row ----------------
__global__ void cls_k(const float* __restrict__ cls, const float* __restrict__ pos,
                      float* __restrict__ out) {
  int n = blockIdx.x * 256 + threadIdx.x;
  if (n >= DM) return;
  float v = cls[n] + pos[n];
  out[n] = v;
  out[(size_t)LSEQ * DM + n] = v;
}

// ---------------- LayerNorm -> bf16 ----------------
__global__ __launch_bounds__(256) void ln_k(const float* __restrict__ tok,
    const float* __restrict__ w, const float* __restrict__ bsh,
    ushort* __restrict__ h) {
  int row = blockIdx.x;
  const float* xr = tok + (size_t)row * DM;
  int tid = threadIdx.x;
  float v[4];
  #pragma unroll
  for (int i = 0; i < 4; ++i) v[i] = xr[tid + 256 * i];
  float s = v[0] + v[1] + v[2] + v[3];
  float s2 = v[0] * v[0] + v[1] * v[1] + v[2] * v[2] + v[3] * v[3];
  #pragma unroll
  for (int off = 32; off; off >>= 1) { s += __shfl_xor(s, off); s2 += __shfl_xor(s2, off); }
  __shared__ float ps[4], ps2[4];
  if ((tid & 63) == 0) { ps[tid >> 6] = s; ps2[tid >> 6] = s2; }
  __syncthreads();
  s = ps[0] + ps[1] + ps[2] + ps[3];
  s2 = ps2[0] + ps2[1] + ps2[2] + ps2[3];
  float mean = s * (1.f / DM);
  float var = s2 * (1.f / DM) - mean * mean;
  float inv = rsqrtf(var + 1e-5f);
  #pragma unroll
  for (int i = 0; i < 4; ++i) {
    int c = tid + 256 * i;
    h[(size_t)row * DM + c] = f2bf((v[i] - mean) * inv * w[c] + bsh[c]);
  }
}

// ---------------- causal depthwise conv + silu -> bf16 (also zeroes dbl) --------
__global__ void conv_silu_k(const float* __restrict__ xc, const float* __restrict__ cw,
                            const float* __restrict__ cb, ushort* __restrict__ ubf,
                            float* __restrict__ dbl0) {
  int idx = blockIdx.x * 256 + threadIdx.x;
  if (idx < MROWS * 96) dbl0[idx] = 0.f;
  if (idx >= MROWS * DI) return;
  int d = idx & (DI - 1);
  int ro = idx >> 11;
  int l = ro % LSEQ;
  float acc = cb[d];
  #pragma unroll
  for (int k = 0; k < 4; ++k) {
    int ll = l - 3 + k;
    if (ll >= 0) acc += xc[(size_t)(ro - 3 + k) * DI + d] * cw[d * 4 + k];
  }
  ubf[idx] = f2bf(acc / (1.f + __expf(-acc)));
}

// ---------------- chunked selective scan ----------------
__global__ __launch_bounds__(256) void scan1_k(
    const ushort* __restrict__ dt, const ushort* __restrict__ ubf,
    const float* __restrict__ dbl, const float* __restrict__ alog,
    float* __restrict__ Ap, float* __restrict__ He)
{
  int d = blockIdx.x * 256 + threadIdx.x;
  int b = blockIdx.y, c = blockIdx.z;
  int t0 = c * LC, t1 = t0 + LC; if (t1 > LSEQ) t1 = LSEQ;
  float Ad[DSTATE], ap[DSTATE], h[DSTATE];
  #pragma unroll
  for (int s = 0; s < DSTATE; ++s) {
    Ad[s] = -__expf(alog[d * DSTATE + s]); ap[s] = 1.f; h[s] = 0.f;
  }
  for (int t = t0; t < t1; ++t) {
    size_t ro = (size_t)b * LSEQ + t;
    float dtv = bf2f(dt[ro * DI + d]);
    float du = dtv * bf2f(ubf[ro * DI + d]);
    const float* r = dbl + ro * 96;
    #pragma unroll
    for (int s = 0; s < DSTATE; ++s) {
      float e = __expf(dtv * Ad[s]);
      h[s] = e * h[s] + du * r[64 + s];
      ap[s] *= e;
    }
  }
  size_t o = (((size_t)(b * NC + c)) * DI + d) * DSTATE;
  #pragma unroll
  for (int s = 0; s < DSTATE; ++s) { Ap[o + s] = ap[s]; He[o + s] = h[s]; }
}

// pass 2: combine across chunks, parallel over (d,s); H0 in place into Ap
__global__ __launch_bounds__(256) void scan2_k(
    float* __restrict__ Ap, const float* __restrict__ He)
{
  int ds = blockIdx.x * 256 + threadIdx.x;
  int b = blockIdx.y;
  float h = 0.f;
  for (int c = 0; c < NC; ++c) {
    size_t o = ((size_t)(b * NC + c)) * DI * DSTATE + ds;
    float ap = Ap[o], he = He[o];
    Ap[o] = h;
    h = ap * h + he;
  }
}

// pass 3: re-scan with h0, gated y -> bf16
__global__ __launch_bounds__(256) void scan3_k(
    const ushort* __restrict__ dt, const ushort* __restrict__ ubf,
    const float* __restrict__ dbl, const ushort* __restrict__ zbf,
    const float* __restrict__ alog, const float* __restrict__ dsk,
    const float* __restrict__ H0, ushort* __restrict__ y)
{
  int d = blockIdx.x * 256 + threadIdx.x;
  int b = blockIdx.y, c = blockIdx.z;
  int t0 = c * LC, t1 = t0 + LC; if (t1 > LSEQ) t1 = LSEQ;
  float Ad[DSTATE], h[DSTATE];
  size_t o = (((size_t)(b * NC + c)) * DI + d) * DSTATE;
  #pragma unroll
  for (int s = 0; s < DSTATE; ++s) {
    Ad[s] = -__expf(alog[d * DSTATE + s]);
    h[s] = H0[o + s];
  }
  float Dv = dsk[d];
  for (int t = t0; t < t1; ++t) {
    size_t ro = (size_t)b * LSEQ + t;
    float dtv = bf2f(dt[ro * DI + d]);
    float uv = bf2f(ubf[ro * DI + d]);
    float du = dtv * uv;
    const float* r = dbl + ro * 96;
    float yv = 0.f;
    #pragma unroll
    for (int s = 0; s < DSTATE; ++s) {
      h[s] = __expf(dtv * Ad[s]) * h[s] + du * r[64 + s];
      yv += h[s] * r[80 + s];
    }
    float z = bf2f(zbf[ro * DI + d]);
    y[ro * DI + d] = f2bf((yv + Dv * uv) * (z / (1.f + __expf(-z))));
  }
}

extern "C" void kernel_launch(void* const* d_in, const int* in_sizes, int n_in,
                              void* d_out, int out_size, void* d_ws, size_t ws_size,
                              hipStream_t stream) {
  const float* x         = (const float*)d_in[0];
  const float* patch_w   = (const float*)d_in[1];
  const float* patch_b   = (const float*)d_in[2];
  const float* cls_token = (const float*)d_in[3];
  const float* pos_embed = (const float*)d_in[4];
  const float* ln_w      = (const float*)d_in[5];
  const float* ln_b      = (const float*)d_in[6];
  const float* in_proj_w = (const float*)d_in[7];
  const float* conv_w    = (const float*)d_in[8];
  const float* conv_b    = (const float*)d_in[9];
  const float* x_proj_w  = (const float*)d_in[10];
  const float* dt_proj_w = (const float*)d_in[11];
  const float* dt_proj_b = (const float*)d_in[12];
  const float* A_log     = (const float*)d_in[13];
  const float* D_skip    = (const float*)d_in[14];
  const float* out_proj_w= (const float*)d_in[15];
  float* tok = (float*)d_out;

  char* base = (char*)d_ws;
  float*  xc_buf = (float*)(base);                  //  9,453,568
  ushort* z_bf   = (ushort*)(base + 9453568);       //  4,726,784
  ushort* u_bf   = (ushort*)(base + 14180352);      //  4,726,784
  float*  dbl    = (float*)(base + 18907136);       //    443,136
  ushort* dt_bf  = (ushort*)(base + 19350272);      //  4,726,784
  ushort* h_bf   = (ushort*)(base + 24077056);      //  2,363,392
  ushort* y_bf   = (ushort*)(base + 26440448);      //  4,726,784
  float*  Ap     = (float*)(base + 31167232);       //  8,388,608
  float*  He     = (float*)(base + 39555840);       //  8,388,608
  ushort* wpatch = (ushort*)(base + 47944448);      //  1,572,864
  ushort* wxp    = (ushort*)(base + 49517312);      //  9,437,184
  ushort* wdt    = (ushort*)(base + 58954496);      //  6,291,456
  ushort* wout   = (ushort*)(base + 65245952);      // 100,663,296
  ushort* win    = (ushort*)(base + 165909248);     // 201,326,592 (end ~367MB)
  ushort* patches= (ushort*)xc_buf;                 // alias, pre-layer only

  // ---- one-time (per call) weight conversion to bf16 ----
  f2bf_k<<<4096, 256, 0, stream>>>(patch_w,   wpatch, 1024 * 768);
  f2bf_k<<<4096, 256, 0, stream>>>(x_proj_w,  wxp,    NLAYERS * 96 * DI);
  f2bf_k<<<4096, 256, 0, stream>>>(dt_proj_w, wdt,    NLAYERS * DI * DTR);
  f2bf_k<<<8192, 256, 0, stream>>>(out_proj_w,wout,   NLAYERS * DM * DI);
  f2bf_k<<<8192, 256, 0, stream>>>(in_proj_w, win,    NLAYERS * 2 * DI * DM);

  // ---- patch embed (bf16 MFMA) + pos ----
  im2col_k<<<(BATCH * NP * 768 + 255) / 256, 256, 0, stream>>>(x, patches);
  {
    dim3 gp(DM / 128, (BATCH * NP) / 128);
    gemm_b<0, 3><<<gp, 512, 0, stream>>>(patches, 768, wpatch, 768, tok, DM,
                                         BATCH * NP, DM, 768, patch_b, pos_embed, nullptr);
  }
  cls_k<<<(DM + 255) / 256, 256, 0, stream>>>(cls_token, pos_embed, tok);

  // ---- 24 mamba layers ----
  for (int l = 0; l < NLAYERS; ++l) {
    ln_k<<<MROWS, 256, 0, stream>>>(tok, ln_w + l * DM, ln_b + l * DM, h_bf);

    {
      dim3 g1(2 * DI / 128, (MROWS + 127) / 128);
      gemm_b<0, 4><<<g1, 512, 0, stream>>>(h_bf, DM, win + (size_t)l * 2 * DI * DM, DM,
                                           xc_buf, DI, MROWS, 2 * DI, DM,
                                           nullptr, nullptr, z_bf);
    }

    conv_silu_k<<<(MROWS * DI + 255) / 256, 256, 0, stream>>>(
        xc_buf, conv_w + (size_t)l * DI * 4, conv_b + (size_t)l * DI, u_bf, dbl);

    {
      dim3 g2(8, (MROWS + 63) / 64);
      xproj_k<<<g2, 256, 0, stream>>>(u_bf, wxp + (size_t)l * 96 * DI, dbl, MROWS);
    }

    {
      dim3 g3(DI / 128, (MROWS + 127) / 128);
      gemm_b<1, 5><<<g3, 512, 0, stream>>>(dbl, 96, wdt + (size_t)l * DI * DTR, DTR,
                                           nullptr, 0, MROWS, DI, DTR,
                                           dt_proj_b + (size_t)l * DI, nullptr, dt_bf);
    }

    {
      dim3 gs(DI / 256, BATCH, NC);
      scan1_k<<<gs, 256, 0, stream>>>(dt_bf, u_bf, dbl,
                                      A_log + (size_t)l * DI * DSTATE, Ap, He);
      dim3 gs2(DI * DSTATE / 256, BATCH);
      scan2_k<<<gs2, 256, 0, stream>>>(Ap, He);
      scan3_k<<<gs, 256, 0, stream>>>(dt_bf, u_bf, dbl, z_bf,
                                      A_log + (size_t)l * DI * DSTATE, D_skip + (size_t)l * DI,
                                      Ap, y_bf);
    }

    {
      dim3 g4(DM / 128, (MROWS + 127) / 128);
      gemm_b<0, 1><<<g4, 512, 0, stream>>>(y_bf, DI, wout + (size_t)l * DM * DI, DI,
                                           tok, DM, MROWS, DM, DI, nullptr, nullptr, nullptr);
    }
  }
}